// Round 15
// baseline (168.792 us; speedup 1.0000x reference)
//
#include <hip/hip_runtime.h>
#include <math.h>

typedef float floatx4 __attribute__((ext_vector_type(4)));
typedef short short8 __attribute__((ext_vector_type(8)));
typedef unsigned short ushort4v __attribute__((ext_vector_type(4)));
typedef unsigned short ushort8v __attribute__((ext_vector_type(8)));
typedef unsigned int uint4v __attribute__((ext_vector_type(4)));

#define MARGIN_ 0.1f
#define THRESH_ 0.5f
#define LOG2E_ 1.44269504088896f
#define MCAP 48

__device__ __forceinline__ unsigned short f2bf(float f){
  unsigned int x = __float_as_uint(f);
  x += 0x7FFFu + ((x >> 16) & 1u);   // round-to-nearest-even
  return (unsigned short)(x >> 16);
}
__device__ __forceinline__ float bf2f(unsigned short u){
  return __uint_as_float(((unsigned int)u) << 16);
}

// async global->LDS, 16B per lane. LDS dest = uniform base + lane*16 (HW).
__device__ __forceinline__ void gld16(const unsigned short* g, unsigned short* l){
  __builtin_amdgcn_global_load_lds(
      (const __attribute__((address_space(1))) unsigned int*)(g),
      (__attribute__((address_space(3))) unsigned int*)(l), 16, 0, 0);
}

// ---------------- kernel 1: row L2-normalize f32 -> bf16 ----------------
__global__ __launch_bounds__(64) void k_norm(const float* __restrict__ feats,
                                             unsigned short* __restrict__ fbf){
  const int row = blockIdx.x;
  const int l = threadIdx.x;
  const float* rp = feats + (size_t)row * 512;
  float4 v0 = ((const float4*)rp)[2 * l];
  float4 v1 = ((const float4*)rp)[2 * l + 1];
  float ss = v0.x*v0.x + v0.y*v0.y + v0.z*v0.z + v0.w*v0.w
           + v1.x*v1.x + v1.y*v1.y + v1.z*v1.z + v1.w*v1.w;
  #pragma unroll
  for(int m = 1; m < 64; m <<= 1) ss += __shfl_xor(ss, m);
  const float rn = 1.0f / sqrtf(ss);
  short8 pk;
  pk[0] = (short)f2bf(v0.x*rn); pk[1] = (short)f2bf(v0.y*rn);
  pk[2] = (short)f2bf(v0.z*rn); pk[3] = (short)f2bf(v0.w*rn);
  pk[4] = (short)f2bf(v1.x*rn); pk[5] = (short)f2bf(v1.y*rn);
  pk[6] = (short)f2bf(v1.z*rn); pk[7] = (short)f2bf(v1.w*rn);
  ((short8*)(fbf + (size_t)row * 512))[l] = pk;
}

// ---------------- prep: permuted u16 labels + histogram + member lists ----------------
__global__ __launch_bounds__(256) void k_prep(const int* __restrict__ labels,
                                              unsigned short* __restrict__ labp,
                                              int* __restrict__ cnt,
                                              int* __restrict__ members, int Bn){
  const int i = blockIdx.x * 256 + threadIdx.x;
  if(i < Bn){
    labp[i] = (unsigned short)labels[(i & ~63) + ((i & 3) * 16) + ((i >> 2) & 15)];
    const int l = labels[i];
    const int pos = atomicAdd(&cnt[l], 1);
    if(pos < MCAP) members[l * MCAP + pos] = i;
  }
}

// ---------------- centroids + global sum: C[c][d]; S += C[c] (S pre-zeroed) ----------------
__global__ __launch_bounds__(256) void k_cent(const unsigned short* __restrict__ fbf,
                                              const int* __restrict__ members,
                                              const int* __restrict__ cnt,
                                              float* __restrict__ C,
                                              float* __restrict__ S){
  const int c = blockIdx.x;
  const int t = threadIdx.x;          // dims 2t, 2t+1
  const int m = min(cnt[c], MCAP);
  float a0 = 0.f, a1 = 0.f;
  for(int k = 0; k < m; k++){
    const int j = members[c * MCAP + k];
    const unsigned int w = *(const unsigned int*)(fbf + (size_t)j * 512 + 2 * t);
    a0 += __uint_as_float(w << 16);
    a1 += __uint_as_float(w & 0xFFFF0000u);
  }
  C[(size_t)c * 512 + 2*t]     = a0;
  C[(size_t)c * 512 + 2*t + 1] = a1;
  atomicAdd(&S[2*t],     a0);
  atomicAdd(&S[2*t + 1], a1);
}

// ---------------- symmetric GEMM: compact tri grid + XCD swizzle (r10, proven) ----------------
#define TRI_S(y) ((y)*n - (((y)*((y)-1))>>1))
__global__ __launch_bounds__(256) void k_gemm_sym(const unsigned short* __restrict__ fbf,
                                                  unsigned short* __restrict__ simb,
                                                  int Bn, int nTri){
  const int n = Bn >> 7;
  int i = blockIdx.x;
  int j;
  if((nTri & 7) == 0){ const int c = nTri >> 3; j = (i & 7) * c + (i >> 3); }
  else j = i;
  int by = (int)(((float)(2*n + 1) - sqrtf((float)((2*n+1)*(2*n+1) - 8*j))) * 0.5f);
  if(by < 0) by = 0;
  while(TRI_S(by + 1) <= j) by++;
  while(TRI_S(by) > j) by--;
  const int bx = by + (j - TRI_S(by));
  const bool diag = (by == bx);

  __shared__ __align__(16) unsigned short Ald[128 * 32];
  __shared__ __align__(16) unsigned short Bld[128 * 32];

  const int t = threadIdx.x;
  const int lane = t & 63, wave = t >> 6;
  const int wm = wave >> 1, wn = wave & 1;
  const int lc = lane & 15, lk = lane >> 4;
  const int row0 = by * 128, col0 = bx * 128;

  floatx4 acc[4][4];
  #pragma unroll
  for(int a = 0; a < 4; a++)
    #pragma unroll
    for(int b2 = 0; b2 < 4; b2++) acc[a][b2] = (floatx4){0.f, 0.f, 0.f, 0.f};

  const int rsub  = lane >> 2;
  const int slotg = (lane & 3) ^ ((lane >> 3) & 3);
  const unsigned short* gA0 = fbf + (size_t)(row0 + wave*32 + rsub) * 512 + slotg * 8;
  const unsigned short* gB0 = fbf + (size_t)(col0 + wave*32 + rsub) * 512 + slotg * 8;
  unsigned short* lA0 = Ald + wave * 1024;
  unsigned short* lB0 = Bld + wave * 1024;
  const int kswz = lk ^ ((lc >> 1) & 3);

  for(int k0 = 0; k0 < 512; k0 += 32){
    __syncthreads();
    gld16(gA0 + k0,            lA0);
    gld16(gA0 + 16*512 + k0,   lA0 + 512);
    gld16(gB0 + k0,            lB0);
    gld16(gB0 + 16*512 + k0,   lB0 + 512);
    __syncthreads();
    short8 av[4], bv[4];
    #pragma unroll
    for(int mi = 0; mi < 4; mi++) av[mi] = ((const short8*)Ald)[(wm*64 + mi*16 + lc)*4 + kswz];
    #pragma unroll
    for(int ni = 0; ni < 4; ni++) bv[ni] = ((const short8*)Bld)[(wn*64 + ni*16 + lc)*4 + kswz];
    #pragma unroll
    for(int mi = 0; mi < 4; mi++)
      #pragma unroll
      for(int ni = 0; ni < 4; ni++)
        acc[mi][ni] = __builtin_amdgcn_mfma_f32_16x16x32_bf16(av[mi], bv[ni], acc[mi][ni], 0, 0, 0);
  }

  unsigned short b[4][4][4];   // [mi][ni][r]
  #pragma unroll
  for(int mi = 0; mi < 4; mi++)
    #pragma unroll
    for(int ni = 0; ni < 4; ni++)
      #pragma unroll
      for(int r = 0; r < 4; r++) b[mi][ni][r] = f2bf(acc[mi][ni][r]);

  // normal packed store: position p = lc*4+ni within 64-block (row side)
  #pragma unroll
  for(int mi = 0; mi < 4; mi++){
    #pragma unroll
    for(int r = 0; r < 4; r++){
      const int row = row0 + wm*64 + mi*16 + lk*4 + r;
      ushort4v v;
      v[0] = b[mi][0][r]; v[1] = b[mi][1][r]; v[2] = b[mi][2][r]; v[3] = b[mi][3][r];
      *(ushort4v*)(simb + (size_t)row * Bn + col0 + wn*64 + lc*4) = v;
    }
  }

  // mirrored store (16B): sim row C = col0+wn*64+ni*16+lc, q = 16lk+4r+mi
  if(!diag){
    #pragma unroll
    for(int ni = 0; ni < 4; ni++){
      const size_t crow = (size_t)(col0 + wn*64 + ni*16 + lc) * Bn;
      #pragma unroll
      for(int h = 0; h < 2; h++){
        ushort8v v;
        v[0] = b[0][ni][2*h];   v[1] = b[1][ni][2*h];
        v[2] = b[2][ni][2*h];   v[3] = b[3][ni][2*h];
        v[4] = b[0][ni][2*h+1]; v[5] = b[1][ni][2*h+1];
        v[6] = b[2][ni][2*h+1]; v[7] = b[3][ni][2*h+1];
        *(ushort8v*)(simb + crow + row0 + wm*64 + 16*lk + 8*h) = v;
      }
    }
  }
}

// ---------------- fused: 2-pass streaming, mask-free scan + centroid dots + mine ----------------
// No persistent register arrays -> low VGPR, high occupancy; phase B reloads
// sims (L3-hot) and labels (L2-hot). Self needs no per-element test (r14-proven).
__global__ __launch_bounds__(256) void k_fused(const unsigned short* __restrict__ simb,
                                               const unsigned short* __restrict__ fbf,
                                               const int* __restrict__ labels,
                                               const unsigned short* __restrict__ labp,
                                               const float* __restrict__ C,
                                               const float* __restrict__ S,
                                               const int* __restrict__ cnt,
                                               float* __restrict__ rl,
                                               float* __restrict__ apv,
                                               float* __restrict__ anv, int Bn){
  const int row = blockIdx.x;
  const int t = threadIdx.x, lane = t & 63, wave = t >> 6;
  const unsigned short* srow = simb + (size_t)row * Bn;
  const int labi = labels[row];
  const int npt = Bn >> 11;

  __shared__ float rq0[4], rq1[4], rq2[4], rq3[4], rq4[4];

  // per-row dots: dims 2t, 2t+1 (f32, L2-hot C/S)
  const unsigned int wf = *(const unsigned int*)(fbf + (size_t)row * 512 + 2*t);
  const float f0 = __uint_as_float(wf << 16);
  const float f1 = __uint_as_float(wf & 0xFFFF0000u);
  const float2 cv = *(const float2*)(C + (size_t)labi * 512 + 2*t);
  const float2 s2 = *(const float2*)(S + 2*t);
  float dps   = f0*cv.x + f1*cv.y;
  float dtot  = f0*s2.x + f1*s2.y;
  float dself = f0*f0 + f1*f1;

  // ---- phase A: streaming min/max scan ----
  float mn = INFINITY, mx = -INFINITY;
  for(int c = 0; c < npt; c++){
    const int idx = c * 256 + t;
    const uint4v w4 = ((const uint4v*)srow)[idx];
    const uint4v l4 = ((const uint4v*)labp)[idx];
    #pragma unroll
    for(int k = 0; k < 4; k++){
      const unsigned int w = w4[k];
      const unsigned int lw = l4[k];
      const float slo = __uint_as_float(w << 16);
      const float shi = __uint_as_float(w & 0xFFFF0000u);
      const bool smlo = ((int)(lw & 0xFFFFu) == labi);
      const bool smhi = ((int)(lw >> 16)     == labi);
      mn = fminf(mn, smlo ? slo :  INFINITY);
      mn = fminf(mn, smhi ? shi :  INFINITY);
      mx = fmaxf(mx, smlo ? -INFINITY : slo);
      mx = fmaxf(mx, smhi ? -INFINITY : shi);
    }
  }
  #pragma unroll
  for(int m = 1; m < 64; m <<= 1){
    dps += __shfl_xor(dps, m); dtot += __shfl_xor(dtot, m); dself += __shfl_xor(dself, m);
    mn = fminf(mn, __shfl_xor(mn, m)); mx = fmaxf(mx, __shfl_xor(mx, m));
  }
  if(lane == 0){ rq0[wave] = dps; rq1[wave] = dtot; rq2[wave] = mn; rq3[wave] = mx; rq4[wave] = dself; }
  __syncthreads();
  const float sdself = rq4[0] + rq4[1] + rq4[2] + rq4[3];
  const float bps    = (rq0[0] + rq0[1] + rq0[2] + rq0[3]) - sdself;
  const float btot   = (rq1[0] + rq1[1] + rq1[2] + rq1[3]) - sdself;
  const float minpos = fminf(fminf(rq2[0], rq2[1]), fminf(rq2[2], rq2[3]));
  const float maxneg = fmaxf(fmaxf(rq3[0], rq3[1]), fmaxf(rq3[2], rq3[3]));
  __syncthreads();

  // ---- phase B: streaming mine (reload sims/labels; L3/L2-hot) ----
  const float KP1 = -2.0f * LOG2E_, KP0 = 1.0f * LOG2E_;     // pos: exp(-2s+1)
  const float KN1 = 40.0f * LOG2E_, KN0 = -20.0f * LOG2E_;   // neg: exp(40s-20)
  const float TP = maxneg + MARGIN_;   // psel: same && s < TP (self fails: s~1)
  const float TN = minpos - MARGIN_;   // nsel: !same && s > TN
  float pe = 0.f, ne = 0.f;
  for(int c = 0; c < npt; c++){
    const int idx = c * 256 + t;
    const uint4v w4 = ((const uint4v*)srow)[idx];
    const uint4v l4 = ((const uint4v*)labp)[idx];
    #pragma unroll
    for(int k = 0; k < 4; k++){
      const unsigned int w = w4[k];
      const unsigned int lw = l4[k];
      #pragma unroll
      for(int h = 0; h < 2; h++){
        const float s = h ? __uint_as_float(w & 0xFFFF0000u)
                          : __uint_as_float(w << 16);
        const bool same = ((int)(h ? (lw >> 16) : (lw & 0xFFFFu)) == labi);
        const float ex = exp2f(fmaf(s, same ? KP1 : KN1, same ? KP0 : KN0));
        const bool psel = same && (s < TP);
        const bool nsel = (!same) && (s > TN);
        pe += psel ? ex : 0.f;
        ne += nsel ? ex : 0.f;
      }
    }
  }
  #pragma unroll
  for(int m = 1; m < 64; m <<= 1){
    pe += __shfl_xor(pe, m); ne += __shfl_xor(ne, m);
  }
  if(lane == 0){ rq0[wave] = pe; rq1[wave] = ne; }
  __syncthreads();
  if(t == 0){
    const float spe = rq0[0] + rq0[1] + rq0[2] + rq0[3];
    const float sne = rq1[0] + rq1[1] + rq1[2] + rq1[3];
    const int c = cnt[labi];
    const float pc = (float)(c - 1);
    const float nc = (float)(Bn - c);
    const bool v1 = (pc >= 1.f) && (nc >= 1.f);
    const bool pf = (minpos - MARGIN_ < maxneg);
    const bool nf = (maxneg + MARGIN_ > minpos);
    const bool valid = v1 && pf && nf;
    rl[row]  = valid ? (0.5f * log1pf(spe) + 0.025f * log1pf(sne)) : 0.f;
    apv[row] = v1 ? bps / fmaxf(pc, 1.f) : 0.f;
    anv[row] = v1 ? (btot - bps) / fmaxf(nc, 1.f) : 0.f;
  }
}

// generic (non-8192) fused: two-pass streaming, one row per block (r12-proven)
__global__ __launch_bounds__(256) void k_fused_gen(const unsigned short* __restrict__ simb,
                                                   const int* __restrict__ labels,
                                                   const unsigned short* __restrict__ labp,
                                                   const int* __restrict__ cnt,
                                                   float* __restrict__ rl,
                                                   float* __restrict__ apv,
                                                   float* __restrict__ anv, int Bn){
  const int row = blockIdx.x;
  const int t = threadIdx.x, lane = t & 63, wave = t >> 6;
  const unsigned short* srow = simb + (size_t)row * Bn;
  const int labi = labels[row];
  const int a = row & 63;
  const int selfpos = (row & ~63) + ((a & 15) * 4) + (a >> 4);
  const int npt = Bn >> 11;

  __shared__ float rq0[4], rq1[4], rq2[4], rq3[4];

  float ps = 0.f, tot = 0.f, mn = INFINITY, mx = -INFINITY;
  for(int c2 = 0; c2 < npt; c2++){
    const int idx = c2 * 256 + t;
    const ushort8v svv = ((const ushort8v*)srow)[idx];
    const ushort8v lb = ((const ushort8v*)labp)[idx];
    const int j0 = idx * 8;
    #pragma unroll
    for(int e = 0; e < 8; e++){
      const float s = bf2f(svv[e]);
      const bool same = ((int)lb[e] == labi);
      const bool self = ((j0 + e) == selfpos);
      if(!self) tot += s;
      if(same && !self){ ps += s; mn = fminf(mn, s); }
      if(!same) mx = fmaxf(mx, s);
    }
  }
  #pragma unroll
  for(int m = 1; m < 64; m <<= 1){
    ps += __shfl_xor(ps, m); tot += __shfl_xor(tot, m);
    mn = fminf(mn, __shfl_xor(mn, m)); mx = fmaxf(mx, __shfl_xor(mx, m));
  }
  if(lane == 0){ rq0[wave] = ps; rq1[wave] = tot; rq2[wave] = mn; rq3[wave] = mx; }
  __syncthreads();
  const float bps    = rq0[0] + rq0[1] + rq0[2] + rq0[3];
  const float btot   = rq1[0] + rq1[1] + rq1[2] + rq1[3];
  const float minpos = fminf(fminf(rq2[0], rq2[1]), fminf(rq2[2], rq2[3]));
  const float maxneg = fmaxf(fmaxf(rq3[0], rq3[1]), fmaxf(rq3[2], rq3[3]));
  __syncthreads();

  const float TP = maxneg + MARGIN_;
  const float TN = minpos - MARGIN_;
  float pe = 0.f, ne = 0.f;
  for(int c2 = 0; c2 < npt; c2++){
    const int idx = c2 * 256 + t;
    const ushort8v svv = ((const ushort8v*)srow)[idx];
    const ushort8v lb = ((const ushort8v*)labp)[idx];
    const int j0 = idx * 8;
    #pragma unroll
    for(int e = 0; e < 8; e++){
      const float s = bf2f(svv[e]);
      const bool same = ((int)lb[e] == labi);
      const bool self = ((j0 + e) == selfpos);
      const bool psel = same && !self && (s < TP);
      const bool nsel = (!same) && (s > TN);
      const float ex = exp2f(fmaf(s, psel ? (-2.0f*LOG2E_) : (40.0f*LOG2E_),
                                     psel ? LOG2E_ : (-20.0f*LOG2E_)));
      pe += psel ? ex : 0.f;
      ne += nsel ? ex : 0.f;
    }
  }
  #pragma unroll
  for(int m = 1; m < 64; m <<= 1){
    pe += __shfl_xor(pe, m); ne += __shfl_xor(ne, m);
  }
  if(lane == 0){ rq0[wave] = pe; rq1[wave] = ne; }
  __syncthreads();
  if(t == 0){
    const float spe = rq0[0] + rq0[1] + rq0[2] + rq0[3];
    const float sne = rq1[0] + rq1[1] + rq1[2] + rq1[3];
    const int c = cnt[labi];
    const float pc = (float)(c - 1);
    const float nc = (float)(Bn - c);
    const bool v1 = (pc >= 1.f) && (nc >= 1.f);
    const bool pf = (minpos - MARGIN_ < maxneg);
    const bool nf = (maxneg + MARGIN_ > minpos);
    const bool valid = v1 && pf && nf;
    rl[row]  = valid ? (0.5f * log1pf(spe) + 0.025f * log1pf(sne)) : 0.f;
    apv[row] = v1 ? bps / fmaxf(pc, 1.f) : 0.f;
    anv[row] = v1 ? (btot - bps) / fmaxf(nc, 1.f) : 0.f;
  }
}

// ---------------- sum per-row triples -> per-block partials ----------------
__global__ __launch_bounds__(256) void k_sum(const float* __restrict__ rl,
                                             const float* __restrict__ apv,
                                             const float* __restrict__ anv,
                                             float* __restrict__ blk, int Bn){
  const int t = threadIdx.x;
  const int row = blockIdx.x * 256 + t;
  float r = rl[row], a1 = apv[row], a2 = anv[row];
  #pragma unroll
  for(int off = 32; off; off >>= 1){
    r += __shfl_down(r, off); a1 += __shfl_down(a1, off); a2 += __shfl_down(a2, off);
  }
  __shared__ float red[3][4];
  const int lane = t & 63, wave = t >> 6;
  if(lane == 0){ red[0][wave] = r; red[1][wave] = a1; red[2][wave] = a2; }
  __syncthreads();
  if(t == 0){
    blk[blockIdx.x*3 + 0] = red[0][0] + red[0][1] + red[0][2] + red[0][3];
    blk[blockIdx.x*3 + 1] = red[1][0] + red[1][1] + red[1][2] + red[1][3];
    blk[blockIdx.x*3 + 2] = red[2][0] + red[2][1] + red[2][2] + red[2][3];
  }
}

__global__ void k_final(const float* __restrict__ blk, int nblk, float inv_b,
                        float* __restrict__ out){
  if(threadIdx.x == 0 && blockIdx.x == 0){
    float l = 0, a = 0, n = 0;
    for(int i = 0; i < nblk; i++){ l += blk[i*3]; a += blk[i*3 + 1]; n += blk[i*3 + 2]; }
    out[0] = l * inv_b;
    out[1] = a * inv_b;
    out[2] = n * inv_b;
  }
}

// ================= FALLBACK PATH (ws too small; proven r5 kernels) =================
__global__ __launch_bounds__(256) void k_pass1(const unsigned short* __restrict__ fbf,
                                               const int* __restrict__ labels,
                                               float* __restrict__ part,
                                               int Bn, int ncb){
  __shared__ __align__(16) unsigned short Ald[128 * 32];
  __shared__ __align__(16) unsigned short Bld[128 * 32];
  __shared__ int Lrow[128], Lcol[128];
  __shared__ float Sps[2][128], Stot[2][128], Smin[2][128], Smax[2][128];

  const int t = threadIdx.x;
  const int lane = t & 63, wave = t >> 6;
  const int wm = wave >> 1, wn = wave & 1;
  const int lc = lane & 15, lk = lane >> 4;
  const int row0 = blockIdx.y * 128, col0 = blockIdx.x * 128;

  if(t < 128){
    Lrow[t] = labels[row0 + t];
    Lcol[t] = labels[col0 + t];
  }

  floatx4 acc[4][4];
  #pragma unroll
  for(int i = 0; i < 4; i++)
    #pragma unroll
    for(int j = 0; j < 4; j++) acc[i][j] = (floatx4){0.f, 0.f, 0.f, 0.f};

  const int rsub  = lane >> 2;
  const int slotg = (lane & 3) ^ ((lane >> 3) & 3);
  const unsigned short* gA0 = fbf + (size_t)(row0 + wave*32 + rsub) * 512 + slotg * 8;
  const unsigned short* gB0 = fbf + (size_t)(col0 + wave*32 + rsub) * 512 + slotg * 8;
  unsigned short* lA0 = Ald + wave * 1024;
  unsigned short* lB0 = Bld + wave * 1024;
  const int kswz = lk ^ ((lc >> 1) & 3);

  for(int k0 = 0; k0 < 512; k0 += 32){
    __syncthreads();
    gld16(gA0 + k0,            lA0);
    gld16(gA0 + 16*512 + k0,   lA0 + 512);
    gld16(gB0 + k0,            lB0);
    gld16(gB0 + 16*512 + k0,   lB0 + 512);
    __syncthreads();
    short8 av[4], bv[4];
    #pragma unroll
    for(int mi = 0; mi < 4; mi++) av[mi] = ((const short8*)Ald)[(wm*64 + mi*16 + lc)*4 + kswz];
    #pragma unroll
    for(int ni = 0; ni < 4; ni++) bv[ni] = ((const short8*)Bld)[(wn*64 + ni*16 + lc)*4 + kswz];
    #pragma unroll
    for(int mi = 0; mi < 4; mi++)
      #pragma unroll
      for(int ni = 0; ni < 4; ni++)
        acc[mi][ni] = __builtin_amdgcn_mfma_f32_16x16x32_bf16(av[mi], bv[ni], acc[mi][ni], 0, 0, 0);
  }

  int labj[4], gj[4];
  #pragma unroll
  for(int ni = 0; ni < 4; ni++){
    const int cl = wn*64 + ni*16 + lc;
    labj[ni] = Lcol[cl]; gj[ni] = col0 + cl;
  }
  #pragma unroll
  for(int mi = 0; mi < 4; mi++){
    #pragma unroll
    for(int r = 0; r < 4; r++){
      const int rowl = wm*64 + mi*16 + lk*4 + r;
      const int labi = Lrow[rowl];
      const int gi = row0 + rowl;
      float ps = 0.f, tot = 0.f, mn = INFINITY, mx = -INFINITY;
      #pragma unroll
      for(int ni = 0; ni < 4; ni++){
        const float s = acc[mi][ni][r];
        const bool same = (labi == labj[ni]);
        const bool self = (gi == gj[ni]);
        if(!self) tot += s;
        if(same && !self){ ps += s; mn = fminf(mn, s); }
        if(!same) mx = fmaxf(mx, s);
      }
      #pragma unroll
      for(int m = 1; m < 16; m <<= 1){
        ps += __shfl_xor(ps, m); tot += __shfl_xor(tot, m);
        mn = fminf(mn, __shfl_xor(mn, m)); mx = fmaxf(mx, __shfl_xor(mx, m));
      }
      if(lc == 0){
        Sps[wn][rowl] = ps; Stot[wn][rowl] = tot;
        Smin[wn][rowl] = mn; Smax[wn][rowl] = mx;
      }
    }
  }
  __syncthreads();
  if(t < 128){
    const size_t stride = (size_t)ncb * Bn;
    const size_t base = (size_t)blockIdx.x * Bn + row0 + t;
    part[0*stride + base] = Sps[0][t] + Sps[1][t];
    part[1*stride + base] = Stot[0][t] + Stot[1][t];
    part[2*stride + base] = fminf(Smin[0][t], Smin[1][t]);
    part[3*stride + base] = fmaxf(Smax[0][t], Smax[1][t]);
  }
}

__global__ __launch_bounds__(256) void k_reduce1(const float* __restrict__ part,
                                                 const int* __restrict__ labels,
                                                 const int* __restrict__ cnt,
                                                 float* __restrict__ st,
                                                 int Bn, int ncb){
  const int row = blockIdx.x * 256 + threadIdx.x;
  if(row >= Bn) return;
  const size_t stride = (size_t)ncb * Bn;
  float ps = 0, tot = 0, mn = INFINITY, mx = -INFINITY;
  for(int cb = 0; cb < ncb; cb++){
    const size_t base = (size_t)cb * Bn + row;
    ps  += part[0*stride + base];
    tot += part[1*stride + base];
    mn = fminf(mn, part[2*stride + base]);
    mx = fmaxf(mx, part[3*stride + base]);
  }
  const int c = cnt[labels[row]];
  const float pc = (float)(c - 1);
  const float nc = (float)(Bn - c);
  st[0*Bn + row] = mn;
  st[1*Bn + row] = mx;
  st[2*Bn + row] = ps / fmaxf(pc, 1.f);
  st[3*Bn + row] = (tot - ps) / fmaxf(nc, 1.f);
  st[4*Bn + row] = (pc >= 1.f && nc >= 1.f) ? 1.f : 0.f;
}

__global__ __launch_bounds__(256) void k_pass2(const unsigned short* __restrict__ fbf,
                                               const int* __restrict__ labels,
                                               const float* __restrict__ st,
                                               float* __restrict__ part,
                                               int Bn, int ncb){
  __shared__ __align__(16) unsigned short Ald[128 * 32];
  __shared__ __align__(16) unsigned short Bld[128 * 32];
  __shared__ int Lrow[128], Lcol[128];
  __shared__ float Minp[128], Maxn[128];
  __shared__ float Spe[2][128], Sne[2][128], Spf[2][128], Snf[2][128];

  const int t = threadIdx.x;
  const int lane = t & 63, wave = t >> 6;
  const int wm = wave >> 1, wn = wave & 1;
  const int lc = lane & 15, lk = lane >> 4;
  const int row0 = blockIdx.y * 128, col0 = blockIdx.x * 128;

  if(t < 128){
    Lrow[t] = labels[row0 + t];
    Lcol[t] = labels[col0 + t];
    Minp[t] = st[0*Bn + row0 + t];
    Maxn[t] = st[1*Bn + row0 + t];
  }

  floatx4 acc[4][4];
  #pragma unroll
  for(int i = 0; i < 4; i++)
    #pragma unroll
    for(int j = 0; j < 4; j++) acc[i][j] = (floatx4){0.f, 0.f, 0.f, 0.f};

  const int rsub  = lane >> 2;
  const int slotg = (lane & 3) ^ ((lane >> 3) & 3);
  const unsigned short* gA0 = fbf + (size_t)(row0 + wave*32 + rsub) * 512 + slotg * 8;
  const unsigned short* gB0 = fbf + (size_t)(col0 + wave*32 + rsub) * 512 + slotg * 8;
  unsigned short* lA0 = Ald + wave * 1024;
  unsigned short* lB0 = Bld + wave * 1024;
  const int kswz = lk ^ ((lc >> 1) & 3);

  for(int k0 = 0; k0 < 512; k0 += 32){
    __syncthreads();
    gld16(gA0 + k0,            lA0);
    gld16(gA0 + 16*512 + k0,   lA0 + 512);
    gld16(gB0 + k0,            lB0);
    gld16(gB0 + 16*512 + k0,   lB0 + 512);
    __syncthreads();
    short8 av[4], bv[4];
    #pragma unroll
    for(int mi = 0; mi < 4; mi++) av[mi] = ((const short8*)Ald)[(wm*64 + mi*16 + lc)*4 + kswz];
    #pragma unroll
    for(int ni = 0; ni < 4; ni++) bv[ni] = ((const short8*)Bld)[(wn*64 + ni*16 + lc)*4 + kswz];
    #pragma unroll
    for(int mi = 0; mi < 4; mi++)
      #pragma unroll
      for(int ni = 0; ni < 4; ni++)
        acc[mi][ni] = __builtin_amdgcn_mfma_f32_16x16x32_bf16(av[mi], bv[ni], acc[mi][ni], 0, 0, 0);
  }

  int labj[4], gj[4];
  #pragma unroll
  for(int ni = 0; ni < 4; ni++){
    const int cl = wn*64 + ni*16 + lc;
    labj[ni] = Lcol[cl]; gj[ni] = col0 + cl;
  }
  #pragma unroll
  for(int mi = 0; mi < 4; mi++){
    #pragma unroll
    for(int r = 0; r < 4; r++){
      const int rowl = wm*64 + mi*16 + lk*4 + r;
      const int labi = Lrow[rowl];
      const int gi = row0 + rowl;
      const float mp  = Minp[rowl];
      const float mxn = Maxn[rowl];
      float pe = 0.f, ne = 0.f;
      bool pa = false, na = false;
      #pragma unroll
      for(int ni = 0; ni < 4; ni++){
        const float s = acc[mi][ni][r];
        const bool same = (labi == labj[ni]);
        const bool self = (gi == gj[ni]);
        if(same && !self && (s - MARGIN_ < mxn)){
          pe += __expf(-2.0f * (s - THRESH_)); pa = true;
        }
        if(!same && (s + MARGIN_ > mp)){
          ne += __expf(40.0f * (s - THRESH_)); na = true;
        }
      }
      const unsigned long long bp  = __ballot((int)pa);
      const unsigned long long bn2 = __ballot((int)na);
      #pragma unroll
      for(int m = 1; m < 16; m <<= 1){
        pe += __shfl_xor(pe, m); ne += __shfl_xor(ne, m);
      }
      if(lc == 0){
        Spe[wn][rowl] = pe; Sne[wn][rowl] = ne;
        Spf[wn][rowl] = ((bp  >> (lk*16)) & 0xFFFFull) ? 1.f : 0.f;
        Snf[wn][rowl] = ((bn2 >> (lk*16)) & 0xFFFFull) ? 1.f : 0.f;
      }
    }
  }
  __syncthreads();
  if(t < 128){
    const size_t stride = (size_t)ncb * Bn;
    const size_t base = (size_t)blockIdx.x * Bn + row0 + t;
    part[0*stride + base] = Spe[0][t] + Spe[1][t];
    part[1*stride + base] = Sne[0][t] + Sne[1][t];
    part[2*stride + base] = fmaxf(Spf[0][t], Spf[1][t]);
    part[3*stride + base] = fmaxf(Snf[0][t], Snf[1][t]);
  }
}

__global__ __launch_bounds__(256) void k_reduce2f(const float* __restrict__ part,
                                                  const float* __restrict__ st,
                                                  float* __restrict__ rowloss,
                                                  float* __restrict__ apv,
                                                  float* __restrict__ anv,
                                                  int Bn, int ncb){
  const int row = blockIdx.x * 256 + threadIdx.x;
  if(row >= Bn) return;
  const size_t stride = (size_t)ncb * Bn;
  float pe = 0, ne = 0, pf = 0, nf = 0;
  for(int cb = 0; cb < ncb; cb++){
    const size_t base = (size_t)cb * Bn + row;
    pe += part[0*stride + base]; ne += part[1*stride + base];
    pf = fmaxf(pf, part[2*stride + base]); nf = fmaxf(nf, part[3*stride + base]);
  }
  const float v1 = st[4*Bn + row];
  const bool valid = (v1 > 0.5f) && (pf > 0.5f) && (nf > 0.5f);
  rowloss[row] = valid ? (0.5f * log1pf(pe) + 0.025f * log1pf(ne)) : 0.f;
  apv[row] = (v1 > 0.5f) ? st[2*Bn + row] : 0.f;
  anv[row] = (v1 > 0.5f) ? st[3*Bn + row] : 0.f;
}

extern "C" void kernel_launch(void* const* d_in, const int* in_sizes, int n_in,
                              void* d_out, int out_size, void* d_ws, size_t ws_size,
                              hipStream_t stream){
  const float* feats = (const float*)d_in[0];
  const int* labels = (const int*)d_in[1];
  float* out = (float*)d_out;
  const int Bn  = in_sizes[1];       // 8192
  const int ncb = Bn / 128;          // 64
  const int nTri = ncb * (ncb + 1) / 2;

  char* ws = (char*)d_ws;
  size_t off = 0;
  unsigned short* fbf = (unsigned short*)(ws + off); off += (size_t)Bn * 512 * 2;   // 8 MB
  float* part = (float*)(ws + off); off += (size_t)4 * ncb * Bn * 4;                // 8.4 MB (fallback)
  float* st   = (float*)(ws + off); off += (size_t)5 * Bn * 4;
  int*   cnt  = (int*)(ws + off);   off += 4096;
  unsigned short* labp = (unsigned short*)(ws + off); off += (size_t)Bn * 2;
  off = (off + 255) & ~(size_t)255;
  int*   members = (int*)(ws + off); off += (size_t)512 * MCAP * 4;                 // 98 KB
  float* Cc  = (float*)(ws + off);  off += (size_t)512 * 512 * 4;                   // 1 MB
  float* Sv  = (float*)(ws + off);  off += 512 * 4;
  float* rl   = (float*)(ws + off); off += (size_t)Bn * 4;
  float* apv  = (float*)(ws + off); off += (size_t)Bn * 4;
  float* anv  = (float*)(ws + off); off += (size_t)Bn * 4;
  float* blk  = (float*)(ws + off); off += 4096;
  off = (off + 255) & ~(size_t)255;
  unsigned short* simb = (unsigned short*)(ws + off);
  const size_t need = off + (size_t)Bn * Bn * 2;   // ~152 MB at Bn=8192
  const bool mat = (ws_size >= need);

  (void)hipMemsetAsync(cnt, 0, 512 * sizeof(int), stream);
  (void)hipMemsetAsync(Sv, 0, 512 * sizeof(float), stream);
  k_norm<<<Bn, 64, 0, stream>>>(feats, fbf);
  k_prep<<<(Bn + 255) / 256, 256, 0, stream>>>(labels, labp, cnt, members, Bn);
  if(mat){
    if(Bn == 8192){
      k_cent<<<512, 256, 0, stream>>>(fbf, members, cnt, Cc, Sv);
    }
    k_gemm_sym<<<nTri, 256, 0, stream>>>(fbf, simb, Bn, nTri);
    if(Bn == 8192){
      k_fused<<<Bn, 256, 0, stream>>>(simb, fbf, labels, labp, Cc, Sv, cnt, rl, apv, anv, Bn);
    } else {
      k_fused_gen<<<Bn, 256, 0, stream>>>(simb, labels, labp, cnt, rl, apv, anv, Bn);
    }
  } else {
    dim3 g(ncb, Bn / 128);
    k_pass1<<<g, 256, 0, stream>>>(fbf, labels, part, Bn, ncb);
    k_reduce1<<<Bn / 256, 256, 0, stream>>>(part, labels, cnt, st, Bn, ncb);
    k_pass2<<<g, 256, 0, stream>>>(fbf, labels, st, part, Bn, ncb);
    k_reduce2f<<<Bn / 256, 256, 0, stream>>>(part, st, rl, apv, anv, Bn, ncb);
  }
  k_sum<<<Bn / 256, 256, 0, stream>>>(rl, apv, anv, blk, Bn);
  k_final<<<1, 64, 0, stream>>>(blk, Bn / 256, 1.0f / (float)Bn, out);
}

// Round 16
// 132.893 us; speedup vs baseline: 1.2701x; 1.2701x over previous
//
#include <hip/hip_runtime.h>
#include <math.h>

typedef float floatx4 __attribute__((ext_vector_type(4)));
typedef short short8 __attribute__((ext_vector_type(8)));
typedef unsigned short ushort4v __attribute__((ext_vector_type(4)));
typedef unsigned short ushort8v __attribute__((ext_vector_type(8)));
typedef unsigned int uint4v __attribute__((ext_vector_type(4)));

#define MARGIN_ 0.1f
#define THRESH_ 0.5f
#define LOG2E_ 1.44269504088896f

__device__ __forceinline__ unsigned short f2bf(float f){
  unsigned int x = __float_as_uint(f);
  x += 0x7FFFu + ((x >> 16) & 1u);   // round-to-nearest-even
  return (unsigned short)(x >> 16);
}
__device__ __forceinline__ float bf2f(unsigned short u){
  return __uint_as_float(((unsigned int)u) << 16);
}

// async global->LDS, 16B per lane. LDS dest = uniform base + lane*16 (HW).
__device__ __forceinline__ void gld16(const unsigned short* g, unsigned short* l){
  __builtin_amdgcn_global_load_lds(
      (const __attribute__((address_space(1))) unsigned int*)(g),
      (__attribute__((address_space(3))) unsigned int*)(l), 16, 0, 0);
}

// ---------------- kernel 1: row L2-normalize f32 -> bf16 ----------------
__global__ __launch_bounds__(64) void k_norm(const float* __restrict__ feats,
                                             unsigned short* __restrict__ fbf){
  const int row = blockIdx.x;
  const int l = threadIdx.x;
  const float* rp = feats + (size_t)row * 512;
  float4 v0 = ((const float4*)rp)[2 * l];
  float4 v1 = ((const float4*)rp)[2 * l + 1];
  float ss = v0.x*v0.x + v0.y*v0.y + v0.z*v0.z + v0.w*v0.w
           + v1.x*v1.x + v1.y*v1.y + v1.z*v1.z + v1.w*v1.w;
  #pragma unroll
  for(int m = 1; m < 64; m <<= 1) ss += __shfl_xor(ss, m);
  const float rn = 1.0f / sqrtf(ss);
  short8 pk;
  pk[0] = (short)f2bf(v0.x*rn); pk[1] = (short)f2bf(v0.y*rn);
  pk[2] = (short)f2bf(v0.z*rn); pk[3] = (short)f2bf(v0.w*rn);
  pk[4] = (short)f2bf(v1.x*rn); pk[5] = (short)f2bf(v1.y*rn);
  pk[6] = (short)f2bf(v1.z*rn); pk[7] = (short)f2bf(v1.w*rn);
  ((short8*)(fbf + (size_t)row * 512))[l] = pk;
}

// ---------------- prep: permuted u16 labels + histogram ----------------
__global__ __launch_bounds__(256) void k_prep(const int* __restrict__ labels,
                                              unsigned short* __restrict__ labp,
                                              int* __restrict__ cnt, int Bn){
  const int i = blockIdx.x * 256 + threadIdx.x;
  if(i < Bn){
    labp[i] = (unsigned short)labels[(i & ~63) + ((i & 3) * 16) + ((i >> 2) & 15)];
    atomicAdd(&cnt[labels[i]], 1);
  }
}

// ---------------- symmetric GEMM: compact tri grid + XCD swizzle (r10, proven) ----------------
#define TRI_S(y) ((y)*n - (((y)*((y)-1))>>1))
__global__ __launch_bounds__(256) void k_gemm_sym(const unsigned short* __restrict__ fbf,
                                                  unsigned short* __restrict__ simb,
                                                  int Bn, int nTri){
  const int n = Bn >> 7;
  int i = blockIdx.x;
  int j;
  if((nTri & 7) == 0){ const int c = nTri >> 3; j = (i & 7) * c + (i >> 3); }
  else j = i;
  int by = (int)(((float)(2*n + 1) - sqrtf((float)((2*n+1)*(2*n+1) - 8*j))) * 0.5f);
  if(by < 0) by = 0;
  while(TRI_S(by + 1) <= j) by++;
  while(TRI_S(by) > j) by--;
  const int bx = by + (j - TRI_S(by));
  const bool diag = (by == bx);

  __shared__ __align__(16) unsigned short Ald[128 * 32];
  __shared__ __align__(16) unsigned short Bld[128 * 32];

  const int t = threadIdx.x;
  const int lane = t & 63, wave = t >> 6;
  const int wm = wave >> 1, wn = wave & 1;
  const int lc = lane & 15, lk = lane >> 4;
  const int row0 = by * 128, col0 = bx * 128;

  floatx4 acc[4][4];
  #pragma unroll
  for(int a = 0; a < 4; a++)
    #pragma unroll
    for(int b2 = 0; b2 < 4; b2++) acc[a][b2] = (floatx4){0.f, 0.f, 0.f, 0.f};

  const int rsub  = lane >> 2;
  const int slotg = (lane & 3) ^ ((lane >> 3) & 3);
  const unsigned short* gA0 = fbf + (size_t)(row0 + wave*32 + rsub) * 512 + slotg * 8;
  const unsigned short* gB0 = fbf + (size_t)(col0 + wave*32 + rsub) * 512 + slotg * 8;
  unsigned short* lA0 = Ald + wave * 1024;
  unsigned short* lB0 = Bld + wave * 1024;
  const int kswz = lk ^ ((lc >> 1) & 3);

  for(int k0 = 0; k0 < 512; k0 += 32){
    __syncthreads();
    gld16(gA0 + k0,            lA0);
    gld16(gA0 + 16*512 + k0,   lA0 + 512);
    gld16(gB0 + k0,            lB0);
    gld16(gB0 + 16*512 + k0,   lB0 + 512);
    __syncthreads();
    short8 av[4], bv[4];
    #pragma unroll
    for(int mi = 0; mi < 4; mi++) av[mi] = ((const short8*)Ald)[(wm*64 + mi*16 + lc)*4 + kswz];
    #pragma unroll
    for(int ni = 0; ni < 4; ni++) bv[ni] = ((const short8*)Bld)[(wn*64 + ni*16 + lc)*4 + kswz];
    #pragma unroll
    for(int mi = 0; mi < 4; mi++)
      #pragma unroll
      for(int ni = 0; ni < 4; ni++)
        acc[mi][ni] = __builtin_amdgcn_mfma_f32_16x16x32_bf16(av[mi], bv[ni], acc[mi][ni], 0, 0, 0);
  }

  unsigned short b[4][4][4];   // [mi][ni][r]
  #pragma unroll
  for(int mi = 0; mi < 4; mi++)
    #pragma unroll
    for(int ni = 0; ni < 4; ni++)
      #pragma unroll
      for(int r = 0; r < 4; r++) b[mi][ni][r] = f2bf(acc[mi][ni][r]);

  // normal packed store: position p = lc*4+ni within 64-block (row side)
  #pragma unroll
  for(int mi = 0; mi < 4; mi++){
    #pragma unroll
    for(int r = 0; r < 4; r++){
      const int row = row0 + wm*64 + mi*16 + lk*4 + r;
      ushort4v v;
      v[0] = b[mi][0][r]; v[1] = b[mi][1][r]; v[2] = b[mi][2][r]; v[3] = b[mi][3][r];
      *(ushort4v*)(simb + (size_t)row * Bn + col0 + wn*64 + lc*4) = v;
    }
  }

  // mirrored store (16B): sim row C = col0+wn*64+ni*16+lc, q = 16lk+4r+mi
  if(!diag){
    #pragma unroll
    for(int ni = 0; ni < 4; ni++){
      const size_t crow = (size_t)(col0 + wn*64 + ni*16 + lc) * Bn;
      #pragma unroll
      for(int h = 0; h < 2; h++){
        ushort8v v;
        v[0] = b[0][ni][2*h];   v[1] = b[1][ni][2*h];
        v[2] = b[2][ni][2*h];   v[3] = b[3][ni][2*h];
        v[4] = b[0][ni][2*h+1]; v[5] = b[1][ni][2*h+1];
        v[6] = b[2][ni][2*h+1]; v[7] = b[3][ni][2*h+1];
        *(ushort8v*)(simb + crow + row0 + wm*64 + 16*lk + 8*h) = v;
      }
    }
  }
}

// ---------------- fused: reg-resident, mask-free A (min/max) + B (exp + ps/tot) ----------------
// ps/tot accumulate in phase B (not needed for thresholds); self corrected by one
// broadcast load of sim_ii. Self needs no per-element test (r14-proven): mx excludes
// self by class; mn's sim_ii~1 never wins when pc>=1 (pc=0 rows are invalid anyway);
// pe's s<TP rejects s~1.
template<int NPT>
__global__ __launch_bounds__(256) void k_fused(const unsigned short* __restrict__ simb,
                                               const int* __restrict__ labels,
                                               const unsigned short* __restrict__ labp,
                                               const int* __restrict__ cnt,
                                               float* __restrict__ rl,
                                               float* __restrict__ apv,
                                               float* __restrict__ anv, int Bn){
  const int row = blockIdx.x;
  const int t = threadIdx.x, lane = t & 63, wave = t >> 6;
  const unsigned short* srow = simb + (size_t)row * Bn;
  const int labi = labels[row];
  const int a = row & 63;
  const int selfpos = (row & ~63) + ((a & 15) * 4) + (a >> 4);
  const float sii = bf2f(srow[selfpos]);   // broadcast load (same addr all threads)

  __shared__ float rq0[4], rq1[4], rq2[4], rq3[4];

  uint4v sv[NPT], lb[NPT];

  // ---- phase A: min/max only ----
  float mn = INFINITY, mx = -INFINITY;
  #pragma unroll
  for(int c = 0; c < NPT; c++){
    const int idx = c * 256 + t;
    sv[c] = ((const uint4v*)srow)[idx];
    lb[c] = ((const uint4v*)labp)[idx];
    #pragma unroll
    for(int k = 0; k < 4; k++){
      const unsigned int w = sv[c][k];
      const unsigned int lw = lb[c][k];
      const float slo = __uint_as_float(w << 16);
      const float shi = __uint_as_float(w & 0xFFFF0000u);
      const bool smlo = ((int)(lw & 0xFFFFu) == labi);
      const bool smhi = ((int)(lw >> 16)     == labi);
      mn = fminf(mn, smlo ? slo :  INFINITY);
      mn = fminf(mn, smhi ? shi :  INFINITY);
      mx = fmaxf(mx, smlo ? -INFINITY : slo);
      mx = fmaxf(mx, smhi ? -INFINITY : shi);
    }
  }
  #pragma unroll
  for(int m = 1; m < 64; m <<= 1){
    mn = fminf(mn, __shfl_xor(mn, m)); mx = fmaxf(mx, __shfl_xor(mx, m));
  }
  if(lane == 0){ rq2[wave] = mn; rq3[wave] = mx; }
  __syncthreads();
  const float minpos = fminf(fminf(rq2[0], rq2[1]), fminf(rq2[2], rq2[3]));
  const float maxneg = fmaxf(fmaxf(rq3[0], rq3[1]), fmaxf(rq3[2], rq3[3]));
  __syncthreads();

  // ---- phase B: mine + ps/tot from registers ----
  const float KP1 = -2.0f * LOG2E_, KP0 = 1.0f * LOG2E_;     // pos: exp(-2s+1)
  const float KN1 = 40.0f * LOG2E_, KN0 = -20.0f * LOG2E_;   // neg: exp(40s-20)
  const float TP = maxneg + MARGIN_;   // psel: same && s < TP (self fails: s~1)
  const float TN = minpos - MARGIN_;   // nsel: !same && s > TN
  float pe = 0.f, ne = 0.f, psum = 0.f, tsum = 0.f;
  #pragma unroll
  for(int c = 0; c < NPT; c++){
    #pragma unroll
    for(int k = 0; k < 4; k++){
      const unsigned int w = sv[c][k];
      const unsigned int lw = lb[c][k];
      #pragma unroll
      for(int h = 0; h < 2; h++){
        const float s = h ? __uint_as_float(w & 0xFFFF0000u)
                          : __uint_as_float(w << 16);
        const bool same = ((int)(h ? (lw >> 16) : (lw & 0xFFFFu)) == labi);
        const float ex = exp2f(fmaf(s, same ? KP1 : KN1, same ? KP0 : KN0));
        const bool psel = same && (s < TP);
        const bool nsel = (!same) && (s > TN);
        pe += psel ? ex : 0.f;
        ne += nsel ? ex : 0.f;
        psum += same ? s : 0.f;
        tsum += s;
      }
    }
  }
  #pragma unroll
  for(int m = 1; m < 64; m <<= 1){
    pe += __shfl_xor(pe, m); ne += __shfl_xor(ne, m);
    psum += __shfl_xor(psum, m); tsum += __shfl_xor(tsum, m);
  }
  if(lane == 0){ rq0[wave] = pe; rq1[wave] = ne; rq2[wave] = psum; rq3[wave] = tsum; }
  __syncthreads();
  if(t == 0){
    const float spe = rq0[0] + rq0[1] + rq0[2] + rq0[3];
    const float sne = rq1[0] + rq1[1] + rq1[2] + rq1[3];
    const float bps  = (rq2[0] + rq2[1] + rq2[2] + rq2[3]) - sii;
    const float btot = (rq3[0] + rq3[1] + rq3[2] + rq3[3]) - sii;
    const int c = cnt[labi];
    const float pc = (float)(c - 1);
    const float nc = (float)(Bn - c);
    const bool v1 = (pc >= 1.f) && (nc >= 1.f);
    const bool pf = (minpos - MARGIN_ < maxneg);
    const bool nf = (maxneg + MARGIN_ > minpos);
    const bool valid = v1 && pf && nf;
    rl[row]  = valid ? (0.5f * log1pf(spe) + 0.025f * log1pf(sne)) : 0.f;
    apv[row] = v1 ? bps / fmaxf(pc, 1.f) : 0.f;
    anv[row] = v1 ? (btot - bps) / fmaxf(nc, 1.f) : 0.f;
  }
}

// generic (non-8192) fused: two-pass streaming, one row per block (r12-proven)
__global__ __launch_bounds__(256) void k_fused_gen(const unsigned short* __restrict__ simb,
                                                   const int* __restrict__ labels,
                                                   const unsigned short* __restrict__ labp,
                                                   const int* __restrict__ cnt,
                                                   float* __restrict__ rl,
                                                   float* __restrict__ apv,
                                                   float* __restrict__ anv, int Bn){
  const int row = blockIdx.x;
  const int t = threadIdx.x, lane = t & 63, wave = t >> 6;
  const unsigned short* srow = simb + (size_t)row * Bn;
  const int labi = labels[row];
  const int a = row & 63;
  const int selfpos = (row & ~63) + ((a & 15) * 4) + (a >> 4);
  const int npt = Bn >> 11;

  __shared__ float rq0[4], rq1[4], rq2[4], rq3[4];

  float ps = 0.f, tot = 0.f, mn = INFINITY, mx = -INFINITY;
  for(int c2 = 0; c2 < npt; c2++){
    const int idx = c2 * 256 + t;
    const ushort8v svv = ((const ushort8v*)srow)[idx];
    const ushort8v lb = ((const ushort8v*)labp)[idx];
    const int j0 = idx * 8;
    #pragma unroll
    for(int e = 0; e < 8; e++){
      const float s = bf2f(svv[e]);
      const bool same = ((int)lb[e] == labi);
      const bool self = ((j0 + e) == selfpos);
      if(!self) tot += s;
      if(same && !self){ ps += s; mn = fminf(mn, s); }
      if(!same) mx = fmaxf(mx, s);
    }
  }
  #pragma unroll
  for(int m = 1; m < 64; m <<= 1){
    ps += __shfl_xor(ps, m); tot += __shfl_xor(tot, m);
    mn = fminf(mn, __shfl_xor(mn, m)); mx = fmaxf(mx, __shfl_xor(mx, m));
  }
  if(lane == 0){ rq0[wave] = ps; rq1[wave] = tot; rq2[wave] = mn; rq3[wave] = mx; }
  __syncthreads();
  const float bps    = rq0[0] + rq0[1] + rq0[2] + rq0[3];
  const float btot   = rq1[0] + rq1[1] + rq1[2] + rq1[3];
  const float minpos = fminf(fminf(rq2[0], rq2[1]), fminf(rq2[2], rq2[3]));
  const float maxneg = fmaxf(fmaxf(rq3[0], rq3[1]), fmaxf(rq3[2], rq3[3]));
  __syncthreads();

  const float TP = maxneg + MARGIN_;
  const float TN = minpos - MARGIN_;
  float pe = 0.f, ne = 0.f;
  for(int c2 = 0; c2 < npt; c2++){
    const int idx = c2 * 256 + t;
    const ushort8v svv = ((const ushort8v*)srow)[idx];
    const ushort8v lb = ((const ushort8v*)labp)[idx];
    const int j0 = idx * 8;
    #pragma unroll
    for(int e = 0; e < 8; e++){
      const float s = bf2f(svv[e]);
      const bool same = ((int)lb[e] == labi);
      const bool self = ((j0 + e) == selfpos);
      const bool psel = same && !self && (s < TP);
      const bool nsel = (!same) && (s > TN);
      const float ex = exp2f(fmaf(s, psel ? (-2.0f*LOG2E_) : (40.0f*LOG2E_),
                                     psel ? LOG2E_ : (-20.0f*LOG2E_)));
      pe += psel ? ex : 0.f;
      ne += nsel ? ex : 0.f;
    }
  }
  #pragma unroll
  for(int m = 1; m < 64; m <<= 1){
    pe += __shfl_xor(pe, m); ne += __shfl_xor(ne, m);
  }
  if(lane == 0){ rq0[wave] = pe; rq1[wave] = ne; }
  __syncthreads();
  if(t == 0){
    const float spe = rq0[0] + rq0[1] + rq0[2] + rq0[3];
    const float sne = rq1[0] + rq1[1] + rq1[2] + rq1[3];
    const int c = cnt[labi];
    const float pc = (float)(c - 1);
    const float nc = (float)(Bn - c);
    const bool v1 = (pc >= 1.f) && (nc >= 1.f);
    const bool pf = (minpos - MARGIN_ < maxneg);
    const bool nf = (maxneg + MARGIN_ > minpos);
    const bool valid = v1 && pf && nf;
    rl[row]  = valid ? (0.5f * log1pf(spe) + 0.025f * log1pf(sne)) : 0.f;
    apv[row] = v1 ? bps / fmaxf(pc, 1.f) : 0.f;
    anv[row] = v1 ? (btot - bps) / fmaxf(nc, 1.f) : 0.f;
  }
}

// ---------------- sum per-row triples -> per-block partials ----------------
__global__ __launch_bounds__(256) void k_sum(const float* __restrict__ rl,
                                             const float* __restrict__ apv,
                                             const float* __restrict__ anv,
                                             float* __restrict__ blk, int Bn){
  const int t = threadIdx.x;
  const int row = blockIdx.x * 256 + t;
  float r = rl[row], a1 = apv[row], a2 = anv[row];
  #pragma unroll
  for(int off = 32; off; off >>= 1){
    r += __shfl_down(r, off); a1 += __shfl_down(a1, off); a2 += __shfl_down(a2, off);
  }
  __shared__ float red[3][4];
  const int lane = t & 63, wave = t >> 6;
  if(lane == 0){ red[0][wave] = r; red[1][wave] = a1; red[2][wave] = a2; }
  __syncthreads();
  if(t == 0){
    blk[blockIdx.x*3 + 0] = red[0][0] + red[0][1] + red[0][2] + red[0][3];
    blk[blockIdx.x*3 + 1] = red[1][0] + red[1][1] + red[1][2] + red[1][3];
    blk[blockIdx.x*3 + 2] = red[2][0] + red[2][1] + red[2][2] + red[2][3];
  }
}

__global__ void k_final(const float* __restrict__ blk, int nblk, float inv_b,
                        float* __restrict__ out){
  if(threadIdx.x == 0 && blockIdx.x == 0){
    float l = 0, a = 0, n = 0;
    for(int i = 0; i < nblk; i++){ l += blk[i*3]; a += blk[i*3 + 1]; n += blk[i*3 + 2]; }
    out[0] = l * inv_b;
    out[1] = a * inv_b;
    out[2] = n * inv_b;
  }
}

// ================= FALLBACK PATH (ws too small; proven r5 kernels) =================
__global__ __launch_bounds__(256) void k_pass1(const unsigned short* __restrict__ fbf,
                                               const int* __restrict__ labels,
                                               float* __restrict__ part,
                                               int Bn, int ncb){
  __shared__ __align__(16) unsigned short Ald[128 * 32];
  __shared__ __align__(16) unsigned short Bld[128 * 32];
  __shared__ int Lrow[128], Lcol[128];
  __shared__ float Sps[2][128], Stot[2][128], Smin[2][128], Smax[2][128];

  const int t = threadIdx.x;
  const int lane = t & 63, wave = t >> 6;
  const int wm = wave >> 1, wn = wave & 1;
  const int lc = lane & 15, lk = lane >> 4;
  const int row0 = blockIdx.y * 128, col0 = blockIdx.x * 128;

  if(t < 128){
    Lrow[t] = labels[row0 + t];
    Lcol[t] = labels[col0 + t];
  }

  floatx4 acc[4][4];
  #pragma unroll
  for(int i = 0; i < 4; i++)
    #pragma unroll
    for(int j = 0; j < 4; j++) acc[i][j] = (floatx4){0.f, 0.f, 0.f, 0.f};

  const int rsub  = lane >> 2;
  const int slotg = (lane & 3) ^ ((lane >> 3) & 3);
  const unsigned short* gA0 = fbf + (size_t)(row0 + wave*32 + rsub) * 512 + slotg * 8;
  const unsigned short* gB0 = fbf + (size_t)(col0 + wave*32 + rsub) * 512 + slotg * 8;
  unsigned short* lA0 = Ald + wave * 1024;
  unsigned short* lB0 = Bld + wave * 1024;
  const int kswz = lk ^ ((lc >> 1) & 3);

  for(int k0 = 0; k0 < 512; k0 += 32){
    __syncthreads();
    gld16(gA0 + k0,            lA0);
    gld16(gA0 + 16*512 + k0,   lA0 + 512);
    gld16(gB0 + k0,            lB0);
    gld16(gB0 + 16*512 + k0,   lB0 + 512);
    __syncthreads();
    short8 av[4], bv[4];
    #pragma unroll
    for(int mi = 0; mi < 4; mi++) av[mi] = ((const short8*)Ald)[(wm*64 + mi*16 + lc)*4 + kswz];
    #pragma unroll
    for(int ni = 0; ni < 4; ni++) bv[ni] = ((const short8*)Bld)[(wn*64 + ni*16 + lc)*4 + kswz];
    #pragma unroll
    for(int mi = 0; mi < 4; mi++)
      #pragma unroll
      for(int ni = 0; ni < 4; ni++)
        acc[mi][ni] = __builtin_amdgcn_mfma_f32_16x16x32_bf16(av[mi], bv[ni], acc[mi][ni], 0, 0, 0);
  }

  int labj[4], gj[4];
  #pragma unroll
  for(int ni = 0; ni < 4; ni++){
    const int cl = wn*64 + ni*16 + lc;
    labj[ni] = Lcol[cl]; gj[ni] = col0 + cl;
  }
  #pragma unroll
  for(int mi = 0; mi < 4; mi++){
    #pragma unroll
    for(int r = 0; r < 4; r++){
      const int rowl = wm*64 + mi*16 + lk*4 + r;
      const int labi = Lrow[rowl];
      const int gi = row0 + rowl;
      float ps = 0.f, tot = 0.f, mn = INFINITY, mx = -INFINITY;
      #pragma unroll
      for(int ni = 0; ni < 4; ni++){
        const float s = acc[mi][ni][r];
        const bool same = (labi == labj[ni]);
        const bool self = (gi == gj[ni]);
        if(!self) tot += s;
        if(same && !self){ ps += s; mn = fminf(mn, s); }
        if(!same) mx = fmaxf(mx, s);
      }
      #pragma unroll
      for(int m = 1; m < 16; m <<= 1){
        ps += __shfl_xor(ps, m); tot += __shfl_xor(tot, m);
        mn = fminf(mn, __shfl_xor(mn, m)); mx = fmaxf(mx, __shfl_xor(mx, m));
      }
      if(lc == 0){
        Sps[wn][rowl] = ps; Stot[wn][rowl] = tot;
        Smin[wn][rowl] = mn; Smax[wn][rowl] = mx;
      }
    }
  }
  __syncthreads();
  if(t < 128){
    const size_t stride = (size_t)ncb * Bn;
    const size_t base = (size_t)blockIdx.x * Bn + row0 + t;
    part[0*stride + base] = Sps[0][t] + Sps[1][t];
    part[1*stride + base] = Stot[0][t] + Stot[1][t];
    part[2*stride + base] = fminf(Smin[0][t], Smin[1][t]);
    part[3*stride + base] = fmaxf(Smax[0][t], Smax[1][t]);
  }
}

__global__ __launch_bounds__(256) void k_reduce1(const float* __restrict__ part,
                                                 const int* __restrict__ labels,
                                                 const int* __restrict__ cnt,
                                                 float* __restrict__ st,
                                                 int Bn, int ncb){
  const int row = blockIdx.x * 256 + threadIdx.x;
  if(row >= Bn) return;
  const size_t stride = (size_t)ncb * Bn;
  float ps = 0, tot = 0, mn = INFINITY, mx = -INFINITY;
  for(int cb = 0; cb < ncb; cb++){
    const size_t base = (size_t)cb * Bn + row;
    ps  += part[0*stride + base];
    tot += part[1*stride + base];
    mn = fminf(mn, part[2*stride + base]);
    mx = fmaxf(mx, part[3*stride + base]);
  }
  const int c = cnt[labels[row]];
  const float pc = (float)(c - 1);
  const float nc = (float)(Bn - c);
  st[0*Bn + row] = mn;
  st[1*Bn + row] = mx;
  st[2*Bn + row] = ps / fmaxf(pc, 1.f);
  st[3*Bn + row] = (tot - ps) / fmaxf(nc, 1.f);
  st[4*Bn + row] = (pc >= 1.f && nc >= 1.f) ? 1.f : 0.f;
}

__global__ __launch_bounds__(256) void k_pass2(const unsigned short* __restrict__ fbf,
                                               const int* __restrict__ labels,
                                               const float* __restrict__ st,
                                               float* __restrict__ part,
                                               int Bn, int ncb){
  __shared__ __align__(16) unsigned short Ald[128 * 32];
  __shared__ __align__(16) unsigned short Bld[128 * 32];
  __shared__ int Lrow[128], Lcol[128];
  __shared__ float Minp[128], Maxn[128];
  __shared__ float Spe[2][128], Sne[2][128], Spf[2][128], Snf[2][128];

  const int t = threadIdx.x;
  const int lane = t & 63, wave = t >> 6;
  const int wm = wave >> 1, wn = wave & 1;
  const int lc = lane & 15, lk = lane >> 4;
  const int row0 = blockIdx.y * 128, col0 = blockIdx.x * 128;

  if(t < 128){
    Lrow[t] = labels[row0 + t];
    Lcol[t] = labels[col0 + t];
    Minp[t] = st[0*Bn + row0 + t];
    Maxn[t] = st[1*Bn + row0 + t];
  }

  floatx4 acc[4][4];
  #pragma unroll
  for(int i = 0; i < 4; i++)
    #pragma unroll
    for(int j = 0; j < 4; j++) acc[i][j] = (floatx4){0.f, 0.f, 0.f, 0.f};

  const int rsub  = lane >> 2;
  const int slotg = (lane & 3) ^ ((lane >> 3) & 3);
  const unsigned short* gA0 = fbf + (size_t)(row0 + wave*32 + rsub) * 512 + slotg * 8;
  const unsigned short* gB0 = fbf + (size_t)(col0 + wave*32 + rsub) * 512 + slotg * 8;
  unsigned short* lA0 = Ald + wave * 1024;
  unsigned short* lB0 = Bld + wave * 1024;
  const int kswz = lk ^ ((lc >> 1) & 3);

  for(int k0 = 0; k0 < 512; k0 += 32){
    __syncthreads();
    gld16(gA0 + k0,            lA0);
    gld16(gA0 + 16*512 + k0,   lA0 + 512);
    gld16(gB0 + k0,            lB0);
    gld16(gB0 + 16*512 + k0,   lB0 + 512);
    __syncthreads();
    short8 av[4], bv[4];
    #pragma unroll
    for(int mi = 0; mi < 4; mi++) av[mi] = ((const short8*)Ald)[(wm*64 + mi*16 + lc)*4 + kswz];
    #pragma unroll
    for(int ni = 0; ni < 4; ni++) bv[ni] = ((const short8*)Bld)[(wn*64 + ni*16 + lc)*4 + kswz];
    #pragma unroll
    for(int mi = 0; mi < 4; mi++)
      #pragma unroll
      for(int ni = 0; ni < 4; ni++)
        acc[mi][ni] = __builtin_amdgcn_mfma_f32_16x16x32_bf16(av[mi], bv[ni], acc[mi][ni], 0, 0, 0);
  }

  int labj[4], gj[4];
  #pragma unroll
  for(int ni = 0; ni < 4; ni++){
    const int cl = wn*64 + ni*16 + lc;
    labj[ni] = Lcol[cl]; gj[ni] = col0 + cl;
  }
  #pragma unroll
  for(int mi = 0; mi < 4; mi++){
    #pragma unroll
    for(int r = 0; r < 4; r++){
      const int rowl = wm*64 + mi*16 + lk*4 + r;
      const int labi = Lrow[rowl];
      const int gi = row0 + rowl;
      const float mp  = Minp[rowl];
      const float mxn = Maxn[rowl];
      float pe = 0.f, ne = 0.f;
      bool pa = false, na = false;
      #pragma unroll
      for(int ni = 0; ni < 4; ni++){
        const float s = acc[mi][ni][r];
        const bool same = (labi == labj[ni]);
        const bool self = (gi == gj[ni]);
        if(same && !self && (s - MARGIN_ < mxn)){
          pe += __expf(-2.0f * (s - THRESH_)); pa = true;
        }
        if(!same && (s + MARGIN_ > mp)){
          ne += __expf(40.0f * (s - THRESH_)); na = true;
        }
      }
      const unsigned long long bp  = __ballot((int)pa);
      const unsigned long long bn2 = __ballot((int)na);
      #pragma unroll
      for(int m = 1; m < 16; m <<= 1){
        pe += __shfl_xor(pe, m); ne += __shfl_xor(ne, m);
      }
      if(lc == 0){
        Spe[wn][rowl] = pe; Sne[wn][rowl] = ne;
        Spf[wn][rowl] = ((bp  >> (lk*16)) & 0xFFFFull) ? 1.f : 0.f;
        Snf[wn][rowl] = ((bn2 >> (lk*16)) & 0xFFFFull) ? 1.f : 0.f;
      }
    }
  }
  __syncthreads();
  if(t < 128){
    const size_t stride = (size_t)ncb * Bn;
    const size_t base = (size_t)blockIdx.x * Bn + row0 + t;
    part[0*stride + base] = Spe[0][t] + Spe[1][t];
    part[1*stride + base] = Sne[0][t] + Sne[1][t];
    part[2*stride + base] = fmaxf(Spf[0][t], Spf[1][t]);
    part[3*stride + base] = fmaxf(Snf[0][t], Snf[1][t]);
  }
}

__global__ __launch_bounds__(256) void k_reduce2f(const float* __restrict__ part,
                                                  const float* __restrict__ st,
                                                  float* __restrict__ rowloss,
                                                  float* __restrict__ apv,
                                                  float* __restrict__ anv,
                                                  int Bn, int ncb){
  const int row = blockIdx.x * 256 + threadIdx.x;
  if(row >= Bn) return;
  const size_t stride = (size_t)ncb * Bn;
  float pe = 0, ne = 0, pf = 0, nf = 0;
  for(int cb = 0; cb < ncb; cb++){
    const size_t base = (size_t)cb * Bn + row;
    pe += part[0*stride + base]; ne += part[1*stride + base];
    pf = fmaxf(pf, part[2*stride + base]); nf = fmaxf(nf, part[3*stride + base]);
  }
  const float v1 = st[4*Bn + row];
  const bool valid = (v1 > 0.5f) && (pf > 0.5f) && (nf > 0.5f);
  rowloss[row] = valid ? (0.5f * log1pf(pe) + 0.025f * log1pf(ne)) : 0.f;
  apv[row] = (v1 > 0.5f) ? st[2*Bn + row] : 0.f;
  anv[row] = (v1 > 0.5f) ? st[3*Bn + row] : 0.f;
}

extern "C" void kernel_launch(void* const* d_in, const int* in_sizes, int n_in,
                              void* d_out, int out_size, void* d_ws, size_t ws_size,
                              hipStream_t stream){
  const float* feats = (const float*)d_in[0];
  const int* labels = (const int*)d_in[1];
  float* out = (float*)d_out;
  const int Bn  = in_sizes[1];       // 8192
  const int ncb = Bn / 128;          // 64
  const int nTri = ncb * (ncb + 1) / 2;

  char* ws = (char*)d_ws;
  size_t off = 0;
  unsigned short* fbf = (unsigned short*)(ws + off); off += (size_t)Bn * 512 * 2;   // 8 MB
  float* part = (float*)(ws + off); off += (size_t)4 * ncb * Bn * 4;                // 8.4 MB (fallback)
  float* st   = (float*)(ws + off); off += (size_t)5 * Bn * 4;
  int*   cnt  = (int*)(ws + off);   off += 4096;
  unsigned short* labp = (unsigned short*)(ws + off); off += (size_t)Bn * 2;
  off = (off + 255) & ~(size_t)255;
  float* rl   = (float*)(ws + off); off += (size_t)Bn * 4;
  float* apv  = (float*)(ws + off); off += (size_t)Bn * 4;
  float* anv  = (float*)(ws + off); off += (size_t)Bn * 4;
  float* blk  = (float*)(ws + off); off += 4096;
  off = (off + 255) & ~(size_t)255;
  unsigned short* simb = (unsigned short*)(ws + off);
  const size_t need = off + (size_t)Bn * Bn * 2;   // ~151 MB at Bn=8192
  const bool mat = (ws_size >= need);

  (void)hipMemsetAsync(cnt, 0, 512 * sizeof(int), stream);
  k_norm<<<Bn, 64, 0, stream>>>(feats, fbf);
  k_prep<<<(Bn + 255) / 256, 256, 0, stream>>>(labels, labp, cnt, Bn);
  if(mat){
    k_gemm_sym<<<nTri, 256, 0, stream>>>(fbf, simb, Bn, nTri);
    if(Bn == 8192){
      k_fused<4><<<Bn, 256, 0, stream>>>(simb, labels, labp, cnt, rl, apv, anv, Bn);
    } else {
      k_fused_gen<<<Bn, 256, 0, stream>>>(simb, labels, labp, cnt, rl, apv, anv, Bn);
    }
  } else {
    dim3 g(ncb, Bn / 128);
    k_pass1<<<g, 256, 0, stream>>>(fbf, labels, part, Bn, ncb);
    k_reduce1<<<Bn / 256, 256, 0, stream>>>(part, labels, cnt, st, Bn, ncb);
    k_pass2<<<g, 256, 0, stream>>>(fbf, labels, st, part, Bn, ncb);
    k_reduce2f<<<Bn / 256, 256, 0, stream>>>(part, st, rl, apv, anv, Bn, ncb);
  }
  k_sum<<<Bn / 256, 256, 0, stream>>>(rl, apv, anv, blk, Bn);
  k_final<<<1, 64, 0, stream>>>(blk, Bn / 256, 1.0f / (float)Bn, out);
}

// Round 17
// 130.605 us; speedup vs baseline: 1.2924x; 1.0175x over previous
//
#include <hip/hip_runtime.h>
#include <math.h>

typedef float floatx4 __attribute__((ext_vector_type(4)));
typedef short short8 __attribute__((ext_vector_type(8)));
typedef unsigned short ushort4v __attribute__((ext_vector_type(4)));
typedef unsigned short ushort8v __attribute__((ext_vector_type(8)));
typedef unsigned int uint4v __attribute__((ext_vector_type(4)));

#define MARGIN_ 0.1f
#define THRESH_ 0.5f
#define LOG2E_ 1.44269504088896f

__device__ __forceinline__ unsigned short f2bf(float f){
  unsigned int x = __float_as_uint(f);
  x += 0x7FFFu + ((x >> 16) & 1u);   // round-to-nearest-even
  return (unsigned short)(x >> 16);
}
__device__ __forceinline__ float bf2f(unsigned short u){
  return __uint_as_float(((unsigned int)u) << 16);
}

// async global->LDS, 16B per lane. LDS dest = uniform base + lane*16 (HW).
__device__ __forceinline__ void gld16(const unsigned short* g, unsigned short* l){
  __builtin_amdgcn_global_load_lds(
      (const __attribute__((address_space(1))) unsigned int*)(g),
      (__attribute__((address_space(3))) unsigned int*)(l), 16, 0, 0);
}

// ---------------- norm (4 rows/block) + fused prep ----------------
__global__ __launch_bounds__(256) void k_norm4(const float* __restrict__ feats,
                                               unsigned short* __restrict__ fbf,
                                               const int* __restrict__ labels,
                                               unsigned short* __restrict__ labp,
                                               int* __restrict__ cnt, int Bn){
  const int t = threadIdx.x, wave = t >> 6, l = t & 63;
  const int row = blockIdx.x * 4 + wave;
  const float* rp = feats + (size_t)row * 512;
  float4 v0 = ((const float4*)rp)[2 * l];
  float4 v1 = ((const float4*)rp)[2 * l + 1];
  float ss = v0.x*v0.x + v0.y*v0.y + v0.z*v0.z + v0.w*v0.w
           + v1.x*v1.x + v1.y*v1.y + v1.z*v1.z + v1.w*v1.w;
  #pragma unroll
  for(int m = 1; m < 64; m <<= 1) ss += __shfl_xor(ss, m);
  const float rn = 1.0f / sqrtf(ss);
  short8 pk;
  pk[0] = (short)f2bf(v0.x*rn); pk[1] = (short)f2bf(v0.y*rn);
  pk[2] = (short)f2bf(v0.z*rn); pk[3] = (short)f2bf(v0.w*rn);
  pk[4] = (short)f2bf(v1.x*rn); pk[5] = (short)f2bf(v1.y*rn);
  pk[6] = (short)f2bf(v1.z*rn); pk[7] = (short)f2bf(v1.w*rn);
  ((short8*)(fbf + (size_t)row * 512))[l] = pk;
  // prep: 4 entries per block
  if(t < 4){
    const int i = blockIdx.x * 4 + t;
    labp[i] = (unsigned short)labels[(i & ~63) + ((i & 3) * 16) + ((i >> 2) & 15)];
    atomicAdd(&cnt[labels[i]], 1);
  }
}

// ---------------- symmetric GEMM: compact tri grid + XCD swizzle ----------------
// b[][][] buffer removed: f2bf inline at stores (lower VGPR).
#define TRI_S(y) ((y)*n - (((y)*((y)-1))>>1))
__global__ __launch_bounds__(256) void k_gemm_sym(const unsigned short* __restrict__ fbf,
                                                  unsigned short* __restrict__ simb,
                                                  int Bn, int nTri){
  const int n = Bn >> 7;
  int i = blockIdx.x;
  int j;
  if((nTri & 7) == 0){ const int c = nTri >> 3; j = (i & 7) * c + (i >> 3); }
  else j = i;
  int by = (int)(((float)(2*n + 1) - sqrtf((float)((2*n+1)*(2*n+1) - 8*j))) * 0.5f);
  if(by < 0) by = 0;
  while(TRI_S(by + 1) <= j) by++;
  while(TRI_S(by) > j) by--;
  const int bx = by + (j - TRI_S(by));
  const bool diag = (by == bx);

  __shared__ __align__(16) unsigned short Ald[128 * 32];
  __shared__ __align__(16) unsigned short Bld[128 * 32];

  const int t = threadIdx.x;
  const int lane = t & 63, wave = t >> 6;
  const int wm = wave >> 1, wn = wave & 1;
  const int lc = lane & 15, lk = lane >> 4;
  const int row0 = by * 128, col0 = bx * 128;

  floatx4 acc[4][4];
  #pragma unroll
  for(int a = 0; a < 4; a++)
    #pragma unroll
    for(int b2 = 0; b2 < 4; b2++) acc[a][b2] = (floatx4){0.f, 0.f, 0.f, 0.f};

  const int rsub  = lane >> 2;
  const int slotg = (lane & 3) ^ ((lane >> 3) & 3);
  const unsigned short* gA0 = fbf + (size_t)(row0 + wave*32 + rsub) * 512 + slotg * 8;
  const unsigned short* gB0 = fbf + (size_t)(col0 + wave*32 + rsub) * 512 + slotg * 8;
  unsigned short* lA0 = Ald + wave * 1024;
  unsigned short* lB0 = Bld + wave * 1024;
  const int kswz = lk ^ ((lc >> 1) & 3);

  for(int k0 = 0; k0 < 512; k0 += 32){
    __syncthreads();
    gld16(gA0 + k0,            lA0);
    gld16(gA0 + 16*512 + k0,   lA0 + 512);
    gld16(gB0 + k0,            lB0);
    gld16(gB0 + 16*512 + k0,   lB0 + 512);
    __syncthreads();
    short8 av[4], bv[4];
    #pragma unroll
    for(int mi = 0; mi < 4; mi++) av[mi] = ((const short8*)Ald)[(wm*64 + mi*16 + lc)*4 + kswz];
    #pragma unroll
    for(int ni = 0; ni < 4; ni++) bv[ni] = ((const short8*)Bld)[(wn*64 + ni*16 + lc)*4 + kswz];
    #pragma unroll
    for(int mi = 0; mi < 4; mi++)
      #pragma unroll
      for(int ni = 0; ni < 4; ni++)
        acc[mi][ni] = __builtin_amdgcn_mfma_f32_16x16x32_bf16(av[mi], bv[ni], acc[mi][ni], 0, 0, 0);
  }

  // normal packed store: position p = lc*4+ni within 64-block (row side)
  #pragma unroll
  for(int mi = 0; mi < 4; mi++){
    #pragma unroll
    for(int r = 0; r < 4; r++){
      const int row = row0 + wm*64 + mi*16 + lk*4 + r;
      ushort4v v;
      v[0] = f2bf(acc[mi][0][r]); v[1] = f2bf(acc[mi][1][r]);
      v[2] = f2bf(acc[mi][2][r]); v[3] = f2bf(acc[mi][3][r]);
      *(ushort4v*)(simb + (size_t)row * Bn + col0 + wn*64 + lc*4) = v;
    }
  }

  // mirrored store (16B): sim row C = col0+wn*64+ni*16+lc, q = 16lk+4r+mi
  if(!diag){
    #pragma unroll
    for(int ni = 0; ni < 4; ni++){
      const size_t crow = (size_t)(col0 + wn*64 + ni*16 + lc) * Bn;
      #pragma unroll
      for(int h = 0; h < 2; h++){
        ushort8v v;
        v[0] = f2bf(acc[0][ni][2*h]);   v[1] = f2bf(acc[1][ni][2*h]);
        v[2] = f2bf(acc[2][ni][2*h]);   v[3] = f2bf(acc[3][ni][2*h]);
        v[4] = f2bf(acc[0][ni][2*h+1]); v[5] = f2bf(acc[1][ni][2*h+1]);
        v[6] = f2bf(acc[2][ni][2*h+1]); v[7] = f2bf(acc[3][ni][2*h+1]);
        *(ushort8v*)(simb + crow + row0 + wm*64 + 16*lk + 8*h) = v;
      }
    }
  }
}

// ---------------- fused: reg-resident, mask-free A (min/max) + B (exp + ps/tot) ----------------
template<int NPT>
__global__ __launch_bounds__(256) void k_fused(const unsigned short* __restrict__ simb,
                                               const int* __restrict__ labels,
                                               const unsigned short* __restrict__ labp,
                                               const int* __restrict__ cnt,
                                               float* __restrict__ rl,
                                               float* __restrict__ apv,
                                               float* __restrict__ anv, int Bn){
  const int row = blockIdx.x;
  const int t = threadIdx.x, lane = t & 63, wave = t >> 6;
  const unsigned short* srow = simb + (size_t)row * Bn;
  const int labi = labels[row];
  const int a = row & 63;
  const int selfpos = (row & ~63) + ((a & 15) * 4) + (a >> 4);
  const float sii = bf2f(srow[selfpos]);   // broadcast load

  __shared__ float rq0[4], rq1[4], rq2[4], rq3[4];

  uint4v sv[NPT], lb[NPT];

  // ---- phase A: min/max only ----
  float mn = INFINITY, mx = -INFINITY;
  #pragma unroll
  for(int c = 0; c < NPT; c++){
    const int idx = c * 256 + t;
    sv[c] = ((const uint4v*)srow)[idx];
    lb[c] = ((const uint4v*)labp)[idx];
    #pragma unroll
    for(int k = 0; k < 4; k++){
      const unsigned int w = sv[c][k];
      const unsigned int lw = lb[c][k];
      const float slo = __uint_as_float(w << 16);
      const float shi = __uint_as_float(w & 0xFFFF0000u);
      const bool smlo = ((int)(lw & 0xFFFFu) == labi);
      const bool smhi = ((int)(lw >> 16)     == labi);
      mn = fminf(mn, smlo ? slo :  INFINITY);
      mn = fminf(mn, smhi ? shi :  INFINITY);
      mx = fmaxf(mx, smlo ? -INFINITY : slo);
      mx = fmaxf(mx, smhi ? -INFINITY : shi);
    }
  }
  #pragma unroll
  for(int m = 1; m < 64; m <<= 1){
    mn = fminf(mn, __shfl_xor(mn, m)); mx = fmaxf(mx, __shfl_xor(mx, m));
  }
  if(lane == 0){ rq2[wave] = mn; rq3[wave] = mx; }
  __syncthreads();
  const float minpos = fminf(fminf(rq2[0], rq2[1]), fminf(rq2[2], rq2[3]));
  const float maxneg = fmaxf(fmaxf(rq3[0], rq3[1]), fmaxf(rq3[2], rq3[3]));
  __syncthreads();

  // ---- phase B: mine + ps/tot from registers ----
  const float KP1 = -2.0f * LOG2E_, KP0 = 1.0f * LOG2E_;
  const float KN1 = 40.0f * LOG2E_, KN0 = -20.0f * LOG2E_;
  const float TP = maxneg + MARGIN_;
  const float TN = minpos - MARGIN_;
  float pe = 0.f, ne = 0.f, psum = 0.f, tsum = 0.f;
  #pragma unroll
  for(int c = 0; c < NPT; c++){
    #pragma unroll
    for(int k = 0; k < 4; k++){
      const unsigned int w = sv[c][k];
      const unsigned int lw = lb[c][k];
      #pragma unroll
      for(int h = 0; h < 2; h++){
        const float s = h ? __uint_as_float(w & 0xFFFF0000u)
                          : __uint_as_float(w << 16);
        const bool same = ((int)(h ? (lw >> 16) : (lw & 0xFFFFu)) == labi);
        const float ex = exp2f(fmaf(s, same ? KP1 : KN1, same ? KP0 : KN0));
        const bool psel = same && (s < TP);
        const bool nsel = (!same) && (s > TN);
        pe += psel ? ex : 0.f;
        ne += nsel ? ex : 0.f;
        psum += same ? s : 0.f;
        tsum += s;
      }
    }
  }
  #pragma unroll
  for(int m = 1; m < 64; m <<= 1){
    pe += __shfl_xor(pe, m); ne += __shfl_xor(ne, m);
    psum += __shfl_xor(psum, m); tsum += __shfl_xor(tsum, m);
  }
  if(lane == 0){ rq0[wave] = pe; rq1[wave] = ne; rq2[wave] = psum; rq3[wave] = tsum; }
  __syncthreads();
  if(t == 0){
    const float spe = rq0[0] + rq0[1] + rq0[2] + rq0[3];
    const float sne = rq1[0] + rq1[1] + rq1[2] + rq1[3];
    const float bps  = (rq2[0] + rq2[1] + rq2[2] + rq2[3]) - sii;
    const float btot = (rq3[0] + rq3[1] + rq3[2] + rq3[3]) - sii;
    const int c = cnt[labi];
    const float pc = (float)(c - 1);
    const float nc = (float)(Bn - c);
    const bool v1 = (pc >= 1.f) && (nc >= 1.f);
    const bool pf = (minpos - MARGIN_ < maxneg);
    const bool nf = (maxneg + MARGIN_ > minpos);
    const bool valid = v1 && pf && nf;
    rl[row]  = valid ? (0.5f * log1pf(spe) + 0.025f * log1pf(sne)) : 0.f;
    apv[row] = v1 ? bps / fmaxf(pc, 1.f) : 0.f;
    anv[row] = v1 ? (btot - bps) / fmaxf(nc, 1.f) : 0.f;
  }
}

// generic (non-8192) fused: two-pass streaming, one row per block (r12-proven)
__global__ __launch_bounds__(256) void k_fused_gen(const unsigned short* __restrict__ simb,
                                                   const int* __restrict__ labels,
                                                   const unsigned short* __restrict__ labp,
                                                   const int* __restrict__ cnt,
                                                   float* __restrict__ rl,
                                                   float* __restrict__ apv,
                                                   float* __restrict__ anv, int Bn){
  const int row = blockIdx.x;
  const int t = threadIdx.x, lane = t & 63, wave = t >> 6;
  const unsigned short* srow = simb + (size_t)row * Bn;
  const int labi = labels[row];
  const int a = row & 63;
  const int selfpos = (row & ~63) + ((a & 15) * 4) + (a >> 4);
  const int npt = Bn >> 11;

  __shared__ float rq0[4], rq1[4], rq2[4], rq3[4];

  float ps = 0.f, tot = 0.f, mn = INFINITY, mx = -INFINITY;
  for(int c2 = 0; c2 < npt; c2++){
    const int idx = c2 * 256 + t;
    const ushort8v svv = ((const ushort8v*)srow)[idx];
    const ushort8v lb = ((const ushort8v*)labp)[idx];
    const int j0 = idx * 8;
    #pragma unroll
    for(int e = 0; e < 8; e++){
      const float s = bf2f(svv[e]);
      const bool same = ((int)lb[e] == labi);
      const bool self = ((j0 + e) == selfpos);
      if(!self) tot += s;
      if(same && !self){ ps += s; mn = fminf(mn, s); }
      if(!same) mx = fmaxf(mx, s);
    }
  }
  #pragma unroll
  for(int m = 1; m < 64; m <<= 1){
    ps += __shfl_xor(ps, m); tot += __shfl_xor(tot, m);
    mn = fminf(mn, __shfl_xor(mn, m)); mx = fmaxf(mx, __shfl_xor(mx, m));
  }
  if(lane == 0){ rq0[wave] = ps; rq1[wave] = tot; rq2[wave] = mn; rq3[wave] = mx; }
  __syncthreads();
  const float bps    = rq0[0] + rq0[1] + rq0[2] + rq0[3];
  const float btot   = rq1[0] + rq1[1] + rq1[2] + rq1[3];
  const float minpos = fminf(fminf(rq2[0], rq2[1]), fminf(rq2[2], rq2[3]));
  const float maxneg = fmaxf(fmaxf(rq3[0], rq3[1]), fmaxf(rq3[2], rq3[3]));
  __syncthreads();

  const float TP = maxneg + MARGIN_;
  const float TN = minpos - MARGIN_;
  float pe = 0.f, ne = 0.f;
  for(int c2 = 0; c2 < npt; c2++){
    const int idx = c2 * 256 + t;
    const ushort8v svv = ((const ushort8v*)srow)[idx];
    const ushort8v lb = ((const ushort8v*)labp)[idx];
    const int j0 = idx * 8;
    #pragma unroll
    for(int e = 0; e < 8; e++){
      const float s = bf2f(svv[e]);
      const bool same = ((int)lb[e] == labi);
      const bool self = ((j0 + e) == selfpos);
      const bool psel = same && !self && (s < TP);
      const bool nsel = (!same) && (s > TN);
      const float ex = exp2f(fmaf(s, psel ? (-2.0f*LOG2E_) : (40.0f*LOG2E_),
                                     psel ? LOG2E_ : (-20.0f*LOG2E_)));
      pe += psel ? ex : 0.f;
      ne += nsel ? ex : 0.f;
    }
  }
  #pragma unroll
  for(int m = 1; m < 64; m <<= 1){
    pe += __shfl_xor(pe, m); ne += __shfl_xor(ne, m);
  }
  if(lane == 0){ rq0[wave] = pe; rq1[wave] = ne; }
  __syncthreads();
  if(t == 0){
    const float spe = rq0[0] + rq0[1] + rq0[2] + rq0[3];
    const float sne = rq1[0] + rq1[1] + rq1[2] + rq1[3];
    const int c = cnt[labi];
    const float pc = (float)(c - 1);
    const float nc = (float)(Bn - c);
    const bool v1 = (pc >= 1.f) && (nc >= 1.f);
    const bool pf = (minpos - MARGIN_ < maxneg);
    const bool nf = (maxneg + MARGIN_ > minpos);
    const bool valid = v1 && pf && nf;
    rl[row]  = valid ? (0.5f * log1pf(spe) + 0.025f * log1pf(sne)) : 0.f;
    apv[row] = v1 ? bps / fmaxf(pc, 1.f) : 0.f;
    anv[row] = v1 ? (btot - bps) / fmaxf(nc, 1.f) : 0.f;
  }
}

// ---------------- final: single-kernel deterministic reduction ----------------
__global__ __launch_bounds__(1024) void k_sumfin(const float* __restrict__ rl,
                                                 const float* __restrict__ apv,
                                                 const float* __restrict__ anv,
                                                 float inv_b, float* __restrict__ out,
                                                 int Bn){
  const int t = threadIdx.x, lane = t & 63, wave = t >> 6;   // 16 waves
  float r = 0.f, a1 = 0.f, a2 = 0.f;
  for(int i = t; i < Bn; i += 1024){ r += rl[i]; a1 += apv[i]; a2 += anv[i]; }
  #pragma unroll
  for(int off = 32; off; off >>= 1){
    r += __shfl_down(r, off); a1 += __shfl_down(a1, off); a2 += __shfl_down(a2, off);
  }
  __shared__ float red[3][16];
  if(lane == 0){ red[0][wave] = r; red[1][wave] = a1; red[2][wave] = a2; }
  __syncthreads();
  if(t == 0){
    float L = 0, A = 0, N = 0;
    for(int w = 0; w < 16; w++){ L += red[0][w]; A += red[1][w]; N += red[2][w]; }
    out[0] = L * inv_b;
    out[1] = A * inv_b;
    out[2] = N * inv_b;
  }
}

// ================= FALLBACK PATH (ws too small; proven r5 kernels) =================
__global__ __launch_bounds__(256) void k_pass1(const unsigned short* __restrict__ fbf,
                                               const int* __restrict__ labels,
                                               float* __restrict__ part,
                                               int Bn, int ncb){
  __shared__ __align__(16) unsigned short Ald[128 * 32];
  __shared__ __align__(16) unsigned short Bld[128 * 32];
  __shared__ int Lrow[128], Lcol[128];
  __shared__ float Sps[2][128], Stot[2][128], Smin[2][128], Smax[2][128];

  const int t = threadIdx.x;
  const int lane = t & 63, wave = t >> 6;
  const int wm = wave >> 1, wn = wave & 1;
  const int lc = lane & 15, lk = lane >> 4;
  const int row0 = blockIdx.y * 128, col0 = blockIdx.x * 128;

  if(t < 128){
    Lrow[t] = labels[row0 + t];
    Lcol[t] = labels[col0 + t];
  }

  floatx4 acc[4][4];
  #pragma unroll
  for(int i = 0; i < 4; i++)
    #pragma unroll
    for(int j = 0; j < 4; j++) acc[i][j] = (floatx4){0.f, 0.f, 0.f, 0.f};

  const int rsub  = lane >> 2;
  const int slotg = (lane & 3) ^ ((lane >> 3) & 3);
  const unsigned short* gA0 = fbf + (size_t)(row0 + wave*32 + rsub) * 512 + slotg * 8;
  const unsigned short* gB0 = fbf + (size_t)(col0 + wave*32 + rsub) * 512 + slotg * 8;
  unsigned short* lA0 = Ald + wave * 1024;
  unsigned short* lB0 = Bld + wave * 1024;
  const int kswz = lk ^ ((lc >> 1) & 3);

  for(int k0 = 0; k0 < 512; k0 += 32){
    __syncthreads();
    gld16(gA0 + k0,            lA0);
    gld16(gA0 + 16*512 + k0,   lA0 + 512);
    gld16(gB0 + k0,            lB0);
    gld16(gB0 + 16*512 + k0,   lB0 + 512);
    __syncthreads();
    short8 av[4], bv[4];
    #pragma unroll
    for(int mi = 0; mi < 4; mi++) av[mi] = ((const short8*)Ald)[(wm*64 + mi*16 + lc)*4 + kswz];
    #pragma unroll
    for(int ni = 0; ni < 4; ni++) bv[ni] = ((const short8*)Bld)[(wn*64 + ni*16 + lc)*4 + kswz];
    #pragma unroll
    for(int mi = 0; mi < 4; mi++)
      #pragma unroll
      for(int ni = 0; ni < 4; ni++)
        acc[mi][ni] = __builtin_amdgcn_mfma_f32_16x16x32_bf16(av[mi], bv[ni], acc[mi][ni], 0, 0, 0);
  }

  int labj[4], gj[4];
  #pragma unroll
  for(int ni = 0; ni < 4; ni++){
    const int cl = wn*64 + ni*16 + lc;
    labj[ni] = Lcol[cl]; gj[ni] = col0 + cl;
  }
  #pragma unroll
  for(int mi = 0; mi < 4; mi++){
    #pragma unroll
    for(int r = 0; r < 4; r++){
      const int rowl = wm*64 + mi*16 + lk*4 + r;
      const int labi = Lrow[rowl];
      const int gi = row0 + rowl;
      float ps = 0.f, tot = 0.f, mn = INFINITY, mx = -INFINITY;
      #pragma unroll
      for(int ni = 0; ni < 4; ni++){
        const float s = acc[mi][ni][r];
        const bool same = (labi == labj[ni]);
        const bool self = (gi == gj[ni]);
        if(!self) tot += s;
        if(same && !self){ ps += s; mn = fminf(mn, s); }
        if(!same) mx = fmaxf(mx, s);
      }
      #pragma unroll
      for(int m = 1; m < 16; m <<= 1){
        ps += __shfl_xor(ps, m); tot += __shfl_xor(tot, m);
        mn = fminf(mn, __shfl_xor(mn, m)); mx = fmaxf(mx, __shfl_xor(mx, m));
      }
      if(lc == 0){
        Sps[wn][rowl] = ps; Stot[wn][rowl] = tot;
        Smin[wn][rowl] = mn; Smax[wn][rowl] = mx;
      }
    }
  }
  __syncthreads();
  if(t < 128){
    const size_t stride = (size_t)ncb * Bn;
    const size_t base = (size_t)blockIdx.x * Bn + row0 + t;
    part[0*stride + base] = Sps[0][t] + Sps[1][t];
    part[1*stride + base] = Stot[0][t] + Stot[1][t];
    part[2*stride + base] = fminf(Smin[0][t], Smin[1][t]);
    part[3*stride + base] = fmaxf(Smax[0][t], Smax[1][t]);
  }
}

__global__ __launch_bounds__(256) void k_reduce1(const float* __restrict__ part,
                                                 const int* __restrict__ labels,
                                                 const int* __restrict__ cnt,
                                                 float* __restrict__ st,
                                                 int Bn, int ncb){
  const int row = blockIdx.x * 256 + threadIdx.x;
  if(row >= Bn) return;
  const size_t stride = (size_t)ncb * Bn;
  float ps = 0, tot = 0, mn = INFINITY, mx = -INFINITY;
  for(int cb = 0; cb < ncb; cb++){
    const size_t base = (size_t)cb * Bn + row;
    ps  += part[0*stride + base];
    tot += part[1*stride + base];
    mn = fminf(mn, part[2*stride + base]);
    mx = fmaxf(mx, part[3*stride + base]);
  }
  const int c = cnt[labels[row]];
  const float pc = (float)(c - 1);
  const float nc = (float)(Bn - c);
  st[0*Bn + row] = mn;
  st[1*Bn + row] = mx;
  st[2*Bn + row] = ps / fmaxf(pc, 1.f);
  st[3*Bn + row] = (tot - ps) / fmaxf(nc, 1.f);
  st[4*Bn + row] = (pc >= 1.f && nc >= 1.f) ? 1.f : 0.f;
}

__global__ __launch_bounds__(256) void k_pass2(const unsigned short* __restrict__ fbf,
                                               const int* __restrict__ labels,
                                               const float* __restrict__ st,
                                               float* __restrict__ part,
                                               int Bn, int ncb){
  __shared__ __align__(16) unsigned short Ald[128 * 32];
  __shared__ __align__(16) unsigned short Bld[128 * 32];
  __shared__ int Lrow[128], Lcol[128];
  __shared__ float Minp[128], Maxn[128];
  __shared__ float Spe[2][128], Sne[2][128], Spf[2][128], Snf[2][128];

  const int t = threadIdx.x;
  const int lane = t & 63, wave = t >> 6;
  const int wm = wave >> 1, wn = wave & 1;
  const int lc = lane & 15, lk = lane >> 4;
  const int row0 = blockIdx.y * 128, col0 = blockIdx.x * 128;

  if(t < 128){
    Lrow[t] = labels[row0 + t];
    Lcol[t] = labels[col0 + t];
    Minp[t] = st[0*Bn + row0 + t];
    Maxn[t] = st[1*Bn + row0 + t];
  }

  floatx4 acc[4][4];
  #pragma unroll
  for(int i = 0; i < 4; i++)
    #pragma unroll
    for(int j = 0; j < 4; j++) acc[i][j] = (floatx4){0.f, 0.f, 0.f, 0.f};

  const int rsub  = lane >> 2;
  const int slotg = (lane & 3) ^ ((lane >> 3) & 3);
  const unsigned short* gA0 = fbf + (size_t)(row0 + wave*32 + rsub) * 512 + slotg * 8;
  const unsigned short* gB0 = fbf + (size_t)(col0 + wave*32 + rsub) * 512 + slotg * 8;
  unsigned short* lA0 = Ald + wave * 1024;
  unsigned short* lB0 = Bld + wave * 1024;
  const int kswz = lk ^ ((lc >> 1) & 3);

  for(int k0 = 0; k0 < 512; k0 += 32){
    __syncthreads();
    gld16(gA0 + k0,            lA0);
    gld16(gA0 + 16*512 + k0,   lA0 + 512);
    gld16(gB0 + k0,            lB0);
    gld16(gB0 + 16*512 + k0,   lB0 + 512);
    __syncthreads();
    short8 av[4], bv[4];
    #pragma unroll
    for(int mi = 0; mi < 4; mi++) av[mi] = ((const short8*)Ald)[(wm*64 + mi*16 + lc)*4 + kswz];
    #pragma unroll
    for(int ni = 0; ni < 4; ni++) bv[ni] = ((const short8*)Bld)[(wn*64 + ni*16 + lc)*4 + kswz];
    #pragma unroll
    for(int mi = 0; mi < 4; mi++)
      #pragma unroll
      for(int ni = 0; ni < 4; ni++)
        acc[mi][ni] = __builtin_amdgcn_mfma_f32_16x16x32_bf16(av[mi], bv[ni], acc[mi][ni], 0, 0, 0);
  }

  int labj[4], gj[4];
  #pragma unroll
  for(int ni = 0; ni < 4; ni++){
    const int cl = wn*64 + ni*16 + lc;
    labj[ni] = Lcol[cl]; gj[ni] = col0 + cl;
  }
  #pragma unroll
  for(int mi = 0; mi < 4; mi++){
    #pragma unroll
    for(int r = 0; r < 4; r++){
      const int rowl = wm*64 + mi*16 + lk*4 + r;
      const int labi = Lrow[rowl];
      const int gi = row0 + rowl;
      const float mp  = Minp[rowl];
      const float mxn = Maxn[rowl];
      float pe = 0.f, ne = 0.f;
      bool pa = false, na = false;
      #pragma unroll
      for(int ni = 0; ni < 4; ni++){
        const float s = acc[mi][ni][r];
        const bool same = (labi == labj[ni]);
        const bool self = (gi == gj[ni]);
        if(same && !self && (s - MARGIN_ < mxn)){
          pe += __expf(-2.0f * (s - THRESH_)); pa = true;
        }
        if(!same && (s + MARGIN_ > mp)){
          ne += __expf(40.0f * (s - THRESH_)); na = true;
        }
      }
      const unsigned long long bp  = __ballot((int)pa);
      const unsigned long long bn2 = __ballot((int)na);
      #pragma unroll
      for(int m = 1; m < 16; m <<= 1){
        pe += __shfl_xor(pe, m); ne += __shfl_xor(ne, m);
      }
      if(lc == 0){
        Spe[wn][rowl] = pe; Sne[wn][rowl] = ne;
        Spf[wn][rowl] = ((bp  >> (lk*16)) & 0xFFFFull) ? 1.f : 0.f;
        Snf[wn][rowl] = ((bn2 >> (lk*16)) & 0xFFFFull) ? 1.f : 0.f;
      }
    }
  }
  __syncthreads();
  if(t < 128){
    const size_t stride = (size_t)ncb * Bn;
    const size_t base = (size_t)blockIdx.x * Bn + row0 + t;
    part[0*stride + base] = Spe[0][t] + Spe[1][t];
    part[1*stride + base] = Sne[0][t] + Sne[1][t];
    part[2*stride + base] = fmaxf(Spf[0][t], Spf[1][t]);
    part[3*stride + base] = fmaxf(Snf[0][t], Snf[1][t]);
  }
}

__global__ __launch_bounds__(256) void k_reduce2f(const float* __restrict__ part,
                                                  const float* __restrict__ st,
                                                  float* __restrict__ rowloss,
                                                  float* __restrict__ apv,
                                                  float* __restrict__ anv,
                                                  int Bn, int ncb){
  const int row = blockIdx.x * 256 + threadIdx.x;
  if(row >= Bn) return;
  const size_t stride = (size_t)ncb * Bn;
  float pe = 0, ne = 0, pf = 0, nf = 0;
  for(int cb = 0; cb < ncb; cb++){
    const size_t base = (size_t)cb * Bn + row;
    pe += part[0*stride + base]; ne += part[1*stride + base];
    pf = fmaxf(pf, part[2*stride + base]); nf = fmaxf(nf, part[3*stride + base]);
  }
  const float v1 = st[4*Bn + row];
  const bool valid = (v1 > 0.5f) && (pf > 0.5f) && (nf > 0.5f);
  rowloss[row] = valid ? (0.5f * log1pf(pe) + 0.025f * log1pf(ne)) : 0.f;
  apv[row] = (v1 > 0.5f) ? st[2*Bn + row] : 0.f;
  anv[row] = (v1 > 0.5f) ? st[3*Bn + row] : 0.f;
}

extern "C" void kernel_launch(void* const* d_in, const int* in_sizes, int n_in,
                              void* d_out, int out_size, void* d_ws, size_t ws_size,
                              hipStream_t stream){
  const float* feats = (const float*)d_in[0];
  const int* labels = (const int*)d_in[1];
  float* out = (float*)d_out;
  const int Bn  = in_sizes[1];       // 8192
  const int ncb = Bn / 128;          // 64
  const int nTri = ncb * (ncb + 1) / 2;

  char* ws = (char*)d_ws;
  size_t off = 0;
  unsigned short* fbf = (unsigned short*)(ws + off); off += (size_t)Bn * 512 * 2;   // 8 MB
  float* part = (float*)(ws + off); off += (size_t)4 * ncb * Bn * 4;                // 8.4 MB (fallback)
  float* st   = (float*)(ws + off); off += (size_t)5 * Bn * 4;
  int*   cnt  = (int*)(ws + off);   off += 4096;
  unsigned short* labp = (unsigned short*)(ws + off); off += (size_t)Bn * 2;
  off = (off + 255) & ~(size_t)255;
  float* rl   = (float*)(ws + off); off += (size_t)Bn * 4;
  float* apv  = (float*)(ws + off); off += (size_t)Bn * 4;
  float* anv  = (float*)(ws + off); off += (size_t)Bn * 4;
  off = (off + 255) & ~(size_t)255;
  unsigned short* simb = (unsigned short*)(ws + off);
  const size_t need = off + (size_t)Bn * Bn * 2;   // ~151 MB at Bn=8192
  const bool mat = (ws_size >= need);

  (void)hipMemsetAsync(cnt, 0, 512 * sizeof(int), stream);
  k_norm4<<<Bn / 4, 256, 0, stream>>>(feats, fbf, labels, labp, cnt, Bn);
  if(mat){
    k_gemm_sym<<<nTri, 256, 0, stream>>>(fbf, simb, Bn, nTri);
    if(Bn == 8192){
      k_fused<4><<<Bn, 256, 0, stream>>>(simb, labels, labp, cnt, rl, apv, anv, Bn);
    } else {
      k_fused_gen<<<Bn, 256, 0, stream>>>(simb, labels, labp, cnt, rl, apv, anv, Bn);
    }
  } else {
    dim3 g(ncb, Bn / 128);
    k_pass1<<<g, 256, 0, stream>>>(fbf, labels, part, Bn, ncb);
    k_reduce1<<<Bn / 256, 256, 0, stream>>>(part, labels, cnt, st, Bn, ncb);
    k_pass2<<<g, 256, 0, stream>>>(fbf, labels, st, part, Bn, ncb);
    k_reduce2f<<<Bn / 256, 256, 0, stream>>>(part, st, rl, apv, anv, Bn, ncb);
  }
  k_sumfin<<<1, 1024, 0, stream>>>(rl, apv, anv, 1.0f / (float)Bn, out, Bn);
}